// Round 7
// baseline (1069.852 us; speedup 1.0000x reference)
//
#include <hip/hip_runtime.h>
#include <hip/hip_bf16.h>
#include <math.h>

// Shapes (fixed): B=4, S=512, PH=4096, N=16384, D=1024, G=128, H=8, L=4, FF=4096, GS=32, HD=128

typedef __bf16 bf16x8_t __attribute__((ext_vector_type(8)));
typedef float  f32x4_t  __attribute__((ext_vector_type(4)));

__device__ __forceinline__ float wredsum(float v){
#pragma unroll
  for (int o = 32; o; o >>= 1) v += __shfl_down(v, o, 64);
  return v;  // valid in lane 0
}

__device__ __forceinline__ bf16x8_t pack8(float4 a, float4 b){
  bf16x8_t v;
  v[0]=(__bf16)a.x; v[1]=(__bf16)a.y; v[2]=(__bf16)a.z; v[3]=(__bf16)a.w;
  v[4]=(__bf16)b.x; v[5]=(__bf16)b.y; v[6]=(__bf16)b.z; v[7]=(__bf16)b.w;
  return v;
}

__device__ __forceinline__ void gload16(const void* g, void* l){
  __builtin_amdgcn_global_load_lds((const __attribute__((address_space(1))) unsigned int*)g,
                                   (__attribute__((address_space(3))) unsigned int*)l, 16, 0, 0);
}

// ---------------------------------------------------------------- fused front-end
// blocks 0..3: FPS; 4..1027: sp GEMV (537 MB); 1028..7299: weight fp32->bf16 (308 MB)
__global__ __launch_bounds__(1024) void fused_front(
  const float* __restrict__ pc, float* __restrict__ centers,
  const float* __restrict__ agg, const float* __restrict__ spw,
  const float* __restrict__ spb, float* __restrict__ x,
  const float* __restrict__ inw, const float* __restrict__ outw,
  const float* __restrict__ w1, const float* __restrict__ w2,
  const float* __restrict__ c1w, __bf16* __restrict__ wbf)
{
  const int bid = blockIdx.x;
  const int tid = threadIdx.x;
  if (bid < 4){
    // ---------------- FPS v3 (validated) ----------------
    const int b = bid;
    const int lane = tid & 63;
    const float* base = pc + (size_t)b * 16384 * 3;
    float px[16], py[16], pz[16], dist[16];
    {
      union { float4 v4[12]; float f[48]; } u;
      const float4* src = (const float4*)(base + tid * 48);
#pragma unroll
      for (int q = 0; q < 12; ++q) u.v4[q] = src[q];
#pragma unroll
      for (int j = 0; j < 16; ++j){
        px[j] = u.f[j*3]; py[j] = u.f[j*3+1]; pz[j] = u.f[j*3+2];
        dist[j] = 1e10f;
      }
    }
    __shared__ unsigned long long keyslot[128];
    for (int i = tid; i < 128; i += 1024) keyslot[i] = 0ULL;
    __syncthreads();
    float cx = base[0], cy = base[1], cz = base[2];
    for (int t = 0; t < 128; ++t){
      if (tid == 0){
        centers[(b*128+t)*3+0] = cx;
        centers[(b*128+t)*3+1] = cy;
        centers[(b*128+t)*3+2] = cz;
      }
      if (t == 127) break;
      float bmax = -1.0f; int bidx = 0;
#pragma unroll
      for (int j = 0; j < 16; ++j){
        float dx = __fsub_rn(px[j], cx);
        float dy = __fsub_rn(py[j], cy);
        float dz = __fsub_rn(pz[j], cz);
        float d  = __fadd_rn(__fadd_rn(__fmul_rn(dx,dx), __fmul_rn(dy,dy)), __fmul_rn(dz,dz));
        float nd = fminf(dist[j], d);
        dist[j] = nd;
        if (nd > bmax){ bmax = nd; bidx = tid*16 + j; }
      }
      unsigned long long key = ((unsigned long long)__float_as_uint(bmax) << 32)
                             | (unsigned long long)(0xFFFFFFFFu - (unsigned)bidx);
#pragma unroll
      for (int o = 32; o; o >>= 1){
        unsigned long long ok = __shfl_down(key, o, 64);
        if (ok > key) key = ok;
      }
      if (lane == 0) atomicMax(&keyslot[t], key);
      __syncthreads();
      const unsigned long long gk = keyslot[t];
      const unsigned gidx = 0xFFFFFFFFu - (unsigned)(gk & 0xFFFFFFFFu);
      const float* cp = base + (size_t)gidx*3;
      cx = cp[0]; cy = cp[1]; cz = cp[2];
    }
  } else if (bid < 1028){
    // ---------------- sp: x0 = agg @ sp_w.T + sp_b ----------------
    __shared__ float ag[4096];
    for (int i = tid; i < 4096; i += 1024) ag[i] = agg[i];
    __syncthreads();
    const int wv = tid >> 6, lane = tid & 63;
    const int rbase = ((bid - 4)*16 + wv)*8;
    for (int rr = 0; rr < 8; ++rr){
      const int row = rbase + rr;
      const float* wp = spw + (size_t)row*1024 + lane*4;
      const float4 w0 = *(const float4*)(wp      );
      const float4 wq1 = *(const float4*)(wp + 256);
      const float4 wq2 = *(const float4*)(wp + 512);
      const float4 wq3 = *(const float4*)(wp + 768);
      float acc[4];
#pragma unroll
      for (int bb = 0; bb < 4; ++bb){
        const float* gp = &ag[bb*1024 + lane*4];
        const float4 g0 = *(const float4*)(gp      );
        const float4 g1 = *(const float4*)(gp + 256);
        const float4 g2 = *(const float4*)(gp + 512);
        const float4 g3 = *(const float4*)(gp + 768);
        acc[bb] = w0.x*g0.x + w0.y*g0.y + w0.z*g0.z + w0.w*g0.w
                + wq1.x*g1.x + wq1.y*g1.y + wq1.z*g1.z + wq1.w*g1.w
                + wq2.x*g2.x + wq2.y*g2.y + wq2.z*g2.z + wq2.w*g2.w
                + wq3.x*g3.x + wq3.y*g3.y + wq3.z*g3.z + wq3.w*g3.w;
      }
      float a0 = wredsum(acc[0]);
      float a1 = wredsum(acc[1]);
      float a2 = wredsum(acc[2]);
      float a3 = wredsum(acc[3]);
      if (lane == 0){
        const float bias = spb[row];
        x[(size_t)0*131072 + row] = a0 + bias;
        x[(size_t)1*131072 + row] = a1 + bias;
        x[(size_t)2*131072 + row] = a2 + bias;
        x[(size_t)3*131072 + row] = a3 + bias;
      }
    }
  } else {
    // ---------------- weight fp32 -> bf16 (all 4 layers + c1) ----------------
    const size_t t = (size_t)(bid - 1028)*1024 + tid;   // exactly 6272*1024 chunks
    const size_t i = t*8;
    const float* src;
    if (i < 50331648){
      const size_t l = i / 12582912, r = i - l*12582912;
      if (r < 3145728)       src = inw  + l*3145728 + r;
      else if (r < 4194304)  src = outw + l*1048576 + (r-3145728);
      else if (r < 8388608)  src = w1   + l*4194304 + (r-4194304);
      else                   src = w2   + l*4194304 + (r-8388608);
    } else src = c1w + (i - 50331648);
    float4 a = *(const float4*)src, bq = *(const float4*)(src+4);
    *(bf16x8_t*)(wbf + i) = pack8(a, bq);
  }
}

// ------------------------------------------------- mean over S (2-stage)
__global__ __launch_bounds__(256) void partial_kernel(const float* __restrict__ lh,
                                                      float* __restrict__ part){
  const int ph = blockIdx.x*256 + threadIdx.x;
  const int sc = blockIdx.y, b = blockIdx.z;
  const float* p = lh + ((size_t)b*512 + sc*64)*4096 + ph;
  float s0=0,s1=0,s2=0,s3=0;
  for (int j = 0; j < 64; j += 4){
    s0 += p[(size_t)(j+0)*4096];
    s1 += p[(size_t)(j+1)*4096];
    s2 += p[(size_t)(j+2)*4096];
    s3 += p[(size_t)(j+3)*4096];
  }
  part[(size_t)(b*8+sc)*4096 + ph] = (s0+s1)+(s2+s3);
}

__global__ __launch_bounds__(256) void combine_kernel(const float* __restrict__ part,
                                                      float* __restrict__ mlh){
  const int i = blockIdx.x*256 + threadIdx.x;
  const int b = i >> 12, ph = i & 4095;
  float s = 0;
#pragma unroll
  for (int sc = 0; sc < 8; ++sc) s += part[(size_t)(b*8+sc)*4096 + ph];
  mlh[i] = s * (1.0f/512.0f);
}

// ------------------------------------------------- agg = mean_lh @ fp_w.T + fp_b
__global__ __launch_bounds__(256) void agg_kernel(const float* __restrict__ mlh,
                                                  const float* __restrict__ fpw,
                                                  const float* __restrict__ fpb,
                                                  float* __restrict__ agg){
  const int o = blockIdx.x*4 + (threadIdx.x>>6);
  const int lane = threadIdx.x & 63;
  const int b = o >> 10, d = o & 1023;
  const float* mp = mlh + b*4096;
  const float* wp = fpw + (size_t)d*4096;
  float s = 0;
#pragma unroll 4
  for (int j = 0; j < 64; ++j){
    int ph = lane + j*64;
    s += mp[ph] * wp[ph];
  }
  s = wredsum(s);
  if (lane == 0) agg[o] = s + fpb[d];
}

// ------------------------------------------------- LayerNorm (optional +pos), bf16 out
__global__ __launch_bounds__(256) void ln_kernel(const float* __restrict__ x,
                                                 const float* __restrict__ pos,
                                                 const float* __restrict__ w,
                                                 const float* __restrict__ bb,
                                                 __bf16* __restrict__ out){
  const int tok = blockIdx.x, g = tok & 127, t = threadIdx.x;
  const int lane = t & 63, wv = t >> 6;
  const float* xr = x + (size_t)tok*1024;
  float v[4];
#pragma unroll
  for (int j = 0; j < 4; ++j){
    int d = t + j*256;
    float val = xr[d];
    if (pos) val += pos[g*1024 + d];
    v[j] = val;
  }
  __shared__ float r1[4], r2[4];
  float s = wredsum(v[0]+v[1]+v[2]+v[3]);
  if (lane == 0) r1[wv] = s;
  __syncthreads();
  const float mean = (r1[0]+r1[1]+r1[2]+r1[3]) * (1.0f/1024.0f);
  float sq = 0;
#pragma unroll
  for (int j = 0; j < 4; ++j){ float d0 = v[j]-mean; sq += d0*d0; }
  sq = wredsum(sq);
  if (lane == 0) r2[wv] = sq;
  __syncthreads();
  const float var = (r2[0]+r2[1]+r2[2]+r2[3]) * (1.0f/1024.0f);
  const float rs = rsqrtf(var + 1e-5f);
#pragma unroll
  for (int j = 0; j < 4; ++j){
    int d = t + j*256;
    out[(size_t)tok*1024 + d] = (__bf16)((v[j]-mean)*rs*w[d] + bb[d]);
  }
}

// ------------------------------------------------- bf16 MFMA full-K GEMM, 128x128 tile, 8 waves
// C = A @ W.T + bias (+fused epilogue). 512 threads: wave w -> (wm=w>>1 in [0,4), wn=w&1).
// Wave tile 32x64 = frag 2(i) x 4(j). Full K per block (no split-K, no partials).
// EPI: 0 bias->bf16 | 1 bias + x residual -> x fp32 (+opt bf16 copy) | 2 bias+GELU->bf16
//      3 bias+BN+ReLU->fp32
template<int EPI>
__global__ __launch_bounds__(512) void gemm_full(
  const __bf16* __restrict__ A, const __bf16* __restrict__ W,
  const float* __restrict__ bias, void* __restrict__ Cv,
  int M, int N, int K,
  float* __restrict__ xres, __bf16* __restrict__ xbcopy,
  const float* __restrict__ bnm, const float* __restrict__ bnv,
  const float* __restrict__ bng, const float* __restrict__ bnb)
{
  __shared__ __bf16 As[128*32];
  __shared__ __bf16 Ws[128*32];
  const int n0 = blockIdx.x*128, m0 = blockIdx.y*128;
  const int tid = threadIdx.x;
  const int lane = tid & 63, w = tid >> 6;
  const int wm = w >> 1, wn = w & 1;
  const int lr = lane & 15, g = lane >> 4;
  const int crow = tid >> 2, cq = tid & 3;   // 512 chunks: row=tid>>2, quarter=tid&3
  const __bf16* ap = A + (size_t)(m0 + crow)*K + cq*8;
  const __bf16* wp = W + (size_t)(n0 + crow)*K + cq*8;
  f32x4_t acc[2][4] = {};
  for (int k0 = 0; k0 < K; k0 += 32){
    __syncthreads();
    gload16(ap + k0, &As[(size_t)tid*8]);
    gload16(wp + k0, &Ws[(size_t)tid*8]);
    __syncthreads();
    bf16x8_t af[2], bf[4];
#pragma unroll
    for (int i = 0; i < 2; ++i)
      af[i] = *(bf16x8_t*)&As[(wm*32 + i*16 + lr)*32 + g*8];
#pragma unroll
    for (int j = 0; j < 4; ++j)
      bf[j] = *(bf16x8_t*)&Ws[(wn*64 + j*16 + lr)*32 + g*8];
#pragma unroll
    for (int i = 0; i < 2; ++i)
#pragma unroll
      for (int j = 0; j < 4; ++j)
        acc[i][j] = __builtin_amdgcn_mfma_f32_16x16x32_bf16(af[i], bf[j], acc[i][j], 0, 0, 0);
  }
#pragma unroll
  for (int i = 0; i < 2; ++i)
#pragma unroll
    for (int j = 0; j < 4; ++j)
#pragma unroll
      for (int r = 0; r < 4; ++r){
        const int row = m0 + wm*32 + i*16 + g*4 + r;
        const int col = n0 + wn*64 + j*16 + lr;
        const size_t idx = (size_t)row*N + col;
        float v = acc[i][j][r] + bias[col];
        if (EPI == 0){
          ((__bf16*)Cv)[idx] = (__bf16)v;
        } else if (EPI == 1){
          v += xres[idx];
          ((float*)Cv)[idx] = v;
          if (xbcopy) xbcopy[idx] = (__bf16)v;
        } else if (EPI == 2){
          v = v * 0.5f * (1.0f + erff(v * 0.70710678118654752440f));
          ((__bf16*)Cv)[idx] = (__bf16)v;
        } else {
          v = (v - bnm[col]) * rsqrtf(bnv[col] + 1e-5f) * bng[col] + bnb[col];
          ((float*)Cv)[idx] = fmaxf(v, 0.0f);
        }
      }
}

// ------------------------------------------------- fused attention v2 (validated R6)
__global__ __launch_bounds__(256) void attn_fused(const __bf16* __restrict__ qkv,
                                                  __bf16* __restrict__ O){
  const int bh = blockIdx.x >> 1, half = blockIdx.x & 1;
  const int b = bh>>3, h = bh&7;
  const int tid = threadIdx.x, w = tid>>6, lane = tid&63;
  const int lr = lane&15, g = lane>>4;
  __shared__ __bf16 vt[128*128];    // V^T swizzled
  __shared__ __bf16 pl[4*2048];     // per-wave P (16x128), swizzled
  {
    const int n = tid >> 1, kh = tid & 1;
    const __bf16* vbase = qkv + (size_t)(b*128)*3072 + 2048 + h*128 + n;
#pragma unroll
    for (int jb = 0; jb < 8; ++jb){
      bf16x8_t pk;
#pragma unroll
      for (int e = 0; e < 8; ++e) pk[e] = vbase[(size_t)(kh*64 + jb*8 + e)*3072];
      const int cb = kh*8 + jb;
      *(bf16x8_t*)&vt[n*128 + ((cb ^ (n&7)) * 8)] = pk;
    }
  }
  const __bf16* qbase = qkv + (size_t)(b*128)*3072 + h*128;
  const __bf16* kbase = qbase + 1024;
  const int qrow0 = half*64 + w*16;
  f32x4_t acc[8] = {};
#pragma unroll
  for (int ks = 0; ks < 4; ++ks){
    bf16x8_t aq, bk[8];
    aq = *(const bf16x8_t*)(qbase + (size_t)(qrow0 + lr)*3072 + ks*32 + g*8);
#pragma unroll
    for (int j = 0; j < 8; ++j)
      bk[j] = *(const bf16x8_t*)(kbase + (size_t)(j*16 + lr)*3072 + ks*32 + g*8);
#pragma unroll
    for (int j = 0; j < 8; ++j)
      acc[j] = __builtin_amdgcn_mfma_f32_16x16x32_bf16(aq, bk[j], acc[j], 0, 0, 0);
  }
  __syncthreads();
  const float scale = 0.088388347648318447f;  // 1/sqrt(128)
#pragma unroll
  for (int r = 0; r < 4; ++r){
    const int row = g*4 + r;
    float sv[8];
    float mx = -1e30f;
#pragma unroll
    for (int j = 0; j < 8; ++j){ sv[j] = acc[j][r]*scale; mx = fmaxf(mx, sv[j]); }
#pragma unroll
    for (int o = 1; o < 16; o <<= 1) mx = fmaxf(mx, __shfl_xor(mx, o, 64));
    float s = 0;
#pragma unroll
    for (int j = 0; j < 8; ++j){ sv[j] = expf(sv[j]-mx); s += sv[j]; }
#pragma unroll
    for (int o = 1; o < 16; o <<= 1) s += __shfl_xor(s, o, 64);
    const float inv = 1.0f/s;
#pragma unroll
    for (int j = 0; j < 8; ++j){
      const int col = j*16 + lr;
      const int slot = (col>>3) ^ (row&7);
      pl[w*2048 + row*128 + slot*8 + (lr&7)] = (__bf16)(sv[j]*inv);
    }
  }
  __syncthreads();
  f32x4_t acc2[8] = {};
#pragma unroll
  for (int ks = 0; ks < 4; ++ks){
    bf16x8_t ap, bv[8];
    {
      const int row = lr;
      const int slot = (ks*4 + g) ^ (row&7);
      ap = *(bf16x8_t*)&pl[w*2048 + row*128 + slot*8];
    }
#pragma unroll
    for (int j = 0; j < 8; ++j){
      const int rowv = j*16 + lr;
      const int cb = ks*4 + g;
      bv[j] = *(bf16x8_t*)&vt[rowv*128 + ((cb ^ (rowv&7))*8)];
    }
#pragma unroll
    for (int j = 0; j < 8; ++j)
      acc2[j] = __builtin_amdgcn_mfma_f32_16x16x32_bf16(ap, bv[j], acc2[j], 0, 0, 0);
  }
#pragma unroll
  for (int j = 0; j < 8; ++j)
#pragma unroll
    for (int r = 0; r < 4; ++r){
      const int row = qrow0 + g*4 + r;
      const int col = j*16 + lr;
      O[(size_t)(b*128+row)*1024 + h*128 + col] = (__bf16)acc2[j][r];
    }
}

// ------------------------------------------------- final head: out = h @ c2_w.T + c2_b + centers
__global__ __launch_bounds__(256) void c2_kernel(const float* __restrict__ hb,
                                                 const float* __restrict__ w,
                                                 const float* __restrict__ bb,
                                                 const float* __restrict__ centers,
                                                 float* __restrict__ out){
  const int o = blockIdx.x*4 + (threadIdx.x>>6);
  const int lane = threadIdx.x & 63;
  const int tok = o / 96, n = o % 96;
  const float* hp = hb + (size_t)tok*1024;
  const float* wp = w + (size_t)n*1024;
  float s = 0;
#pragma unroll 4
  for (int j = 0; j < 16; ++j){
    int k = lane + j*64;
    s += hp[k] * wp[k];
  }
  s = wredsum(s);
  if (lane == 0) out[o] = s + bb[n] + centers[tok*3 + (n % 3)];
}

// =================================================================
extern "C" void kernel_launch(void* const* d_in, const int* in_sizes, int n_in,
                              void* d_out, int out_size, void* d_ws, size_t ws_size,
                              hipStream_t stream){
  const float* lh   = (const float*)d_in[0];
  const float* pc   = (const float*)d_in[1];
  const float* fpw  = (const float*)d_in[2];
  const float* fpb  = (const float*)d_in[3];
  const float* spw  = (const float*)d_in[4];
  const float* spb  = (const float*)d_in[5];
  const float* pos  = (const float*)d_in[6];
  const float* ln1w = (const float*)d_in[7];
  const float* ln1b = (const float*)d_in[8];
  const float* inw  = (const float*)d_in[9];
  const float* inb  = (const float*)d_in[10];
  const float* outw = (const float*)d_in[11];
  const float* outb = (const float*)d_in[12];
  const float* ln2w = (const float*)d_in[13];
  const float* ln2b = (const float*)d_in[14];
  const float* w1   = (const float*)d_in[15];
  const float* b1   = (const float*)d_in[16];
  const float* w2   = (const float*)d_in[17];
  const float* b2   = (const float*)d_in[18];
  const float* c1w  = (const float*)d_in[19];
  const float* c1b  = (const float*)d_in[20];
  const float* bng  = (const float*)d_in[21];
  const float* bnbt = (const float*)d_in[22];
  const float* bnm  = (const float*)d_in[23];
  const float* bnv  = (const float*)d_in[24];
  const float* c2w  = (const float*)d_in[25];
  const float* c2b  = (const float*)d_in[26];
  float* out = (float*)d_out;

  // ---- workspace layout ----
  float* f = (float*)d_ws;
  float* part  = f;              f += 131072;
  float* mlh   = f;              f += 16384;
  float* agg   = f;              f += 4096;
  float* x     = f;              f += 524288;     // residual stream fp32
  float* hc1   = f;              f += 524288;     // c1 out (BN+ReLU) fp32
  float* cent  = f;              f += 2048;       // centers (+pad)
  __bf16* bfp = (__bf16*)f;
  __bf16* xn   = bfp;            bfp += 524288;   // LN out bf16
  __bf16* qkv  = bfp;            bfp += 1572864;
  __bf16* obuf = bfp;            bfp += 524288;
  __bf16* hbf  = bfp;            bfp += 2097152;  // MLP hidden bf16
  __bf16* xbf  = bfp;            bfp += 524288;   // bf16 copy of final x
  __bf16* wbf  = bfp;            bfp += 51380224; // all weights bf16 (4 layers + c1 at +50331648)

  partial_kernel<<<dim3(16,8,4), 256, 0, stream>>>(lh, part);
  combine_kernel<<<64, 256, 0, stream>>>(part, mlh);
  agg_kernel<<<1024, 256, 0, stream>>>(mlh, fpw, fpb, agg);
  fused_front<<<7300, 1024, 0, stream>>>(pc, cent, agg, spw, spb, x,
                                         inw, outw, w1, w2, c1w, wbf);
  ln_kernel<<<512, 256, 0, stream>>>(x, pos, ln1w, ln1b, xn);

  for (int l = 0; l < 4; ++l){
    const __bf16* wl = wbf + (size_t)l*12582912;
    // qkv: 512x3072x1024 (96 blocks, full K)
    gemm_full<0><<<dim3(24,4), 512, 0, stream>>>(xn, wl, inb + l*3072, qkv,
                                                 512, 3072, 1024,
                                                 nullptr, nullptr, nullptr, nullptr, nullptr, nullptr);
    attn_fused<<<64, 256, 0, stream>>>(qkv, obuf);
    // attn-out + residual: 512x1024x1024 (32 blocks)
    gemm_full<1><<<dim3(8,4), 512, 0, stream>>>(obuf, wl + 3145728, outb + l*1024, x,
                                                512, 1024, 1024,
                                                x, nullptr, nullptr, nullptr, nullptr, nullptr);
    ln_kernel<<<512, 256, 0, stream>>>(x, nullptr, ln2w + l*1024, ln2b + l*1024, xn);
    // mlp1 + GELU: 512x4096x1024 (128 blocks)
    gemm_full<2><<<dim3(32,4), 512, 0, stream>>>(xn, wl + 4194304, b1 + l*4096, hbf,
                                                 512, 4096, 1024,
                                                 nullptr, nullptr, nullptr, nullptr, nullptr, nullptr);
    // mlp2 + residual: 512x1024x4096 (32 blocks)
    gemm_full<1><<<dim3(8,4), 512, 0, stream>>>(hbf, wl + 8388608, b2 + l*1024, x,
                                                512, 1024, 4096,
                                                x, (l==3) ? xbf : nullptr, nullptr, nullptr, nullptr, nullptr);
    if (l < 3)
      ln_kernel<<<512, 256, 0, stream>>>(x, pos, ln1w + (l+1)*1024, ln1b + (l+1)*1024, xn);
  }

  // c1 + BN + ReLU: 512x1024x1024 (32 blocks)
  gemm_full<3><<<dim3(8,4), 512, 0, stream>>>(xbf, wbf + 50331648, c1b, hc1,
                                              512, 1024, 1024,
                                              nullptr, nullptr, bnm, bnv, bng, bnbt);
  c2_kernel<<<12288, 256, 0, stream>>>(hc1, c2w, c2b, cent, out);
}

// Round 8
// 872.539 us; speedup vs baseline: 1.2261x; 1.2261x over previous
//
#include <hip/hip_runtime.h>
#include <hip/hip_bf16.h>
#include <math.h>

// Shapes (fixed): B=4, S=512, PH=4096, N=16384, D=1024, G=128, H=8, L=4, FF=4096, GS=32, HD=128

typedef __bf16 bf16x8_t __attribute__((ext_vector_type(8)));
typedef float  f32x4_t  __attribute__((ext_vector_type(4)));

__device__ __forceinline__ float wredsum(float v){
#pragma unroll
  for (int o = 32; o; o >>= 1) v += __shfl_down(v, o, 64);
  return v;  // valid in lane 0
}

__device__ __forceinline__ bf16x8_t pack8(float4 a, float4 b){
  bf16x8_t v;
  v[0]=(__bf16)a.x; v[1]=(__bf16)a.y; v[2]=(__bf16)a.z; v[3]=(__bf16)a.w;
  v[4]=(__bf16)b.x; v[5]=(__bf16)b.y; v[6]=(__bf16)b.z; v[7]=(__bf16)b.w;
  return v;
}

__device__ __forceinline__ void gload16(const void* g, void* l){
  __builtin_amdgcn_global_load_lds((const __attribute__((address_space(1))) unsigned int*)g,
                                   (__attribute__((address_space(3))) unsigned int*)l, 16, 0, 0);
}

// ---------------------------------------------------------------- fused front-end
// blocks 0..3: FPS; 4..1027: sp GEMV (537 MB); 1028..7299: weight fp32->bf16 (308 MB)
__global__ __launch_bounds__(1024) void fused_front(
  const float* __restrict__ pc, float* __restrict__ centers,
  const float* __restrict__ agg, const float* __restrict__ spw,
  const float* __restrict__ spb, float* __restrict__ x,
  const float* __restrict__ inw, const float* __restrict__ outw,
  const float* __restrict__ w1, const float* __restrict__ w2,
  const float* __restrict__ c1w, __bf16* __restrict__ wbf)
{
  const int bid = blockIdx.x;
  const int tid = threadIdx.x;
  if (bid < 4){
    // ---------------- FPS v3 (validated) ----------------
    const int b = bid;
    const int lane = tid & 63;
    const float* base = pc + (size_t)b * 16384 * 3;
    float px[16], py[16], pz[16], dist[16];
    {
      union { float4 v4[12]; float f[48]; } u;
      const float4* src = (const float4*)(base + tid * 48);
#pragma unroll
      for (int q = 0; q < 12; ++q) u.v4[q] = src[q];
#pragma unroll
      for (int j = 0; j < 16; ++j){
        px[j] = u.f[j*3]; py[j] = u.f[j*3+1]; pz[j] = u.f[j*3+2];
        dist[j] = 1e10f;
      }
    }
    __shared__ unsigned long long keyslot[128];
    for (int i = tid; i < 128; i += 1024) keyslot[i] = 0ULL;
    __syncthreads();
    float cx = base[0], cy = base[1], cz = base[2];
    for (int t = 0; t < 128; ++t){
      if (tid == 0){
        centers[(b*128+t)*3+0] = cx;
        centers[(b*128+t)*3+1] = cy;
        centers[(b*128+t)*3+2] = cz;
      }
      if (t == 127) break;
      float bmax = -1.0f; int bidx = 0;
#pragma unroll
      for (int j = 0; j < 16; ++j){
        float dx = __fsub_rn(px[j], cx);
        float dy = __fsub_rn(py[j], cy);
        float dz = __fsub_rn(pz[j], cz);
        float d  = __fadd_rn(__fadd_rn(__fmul_rn(dx,dx), __fmul_rn(dy,dy)), __fmul_rn(dz,dz));
        float nd = fminf(dist[j], d);
        dist[j] = nd;
        if (nd > bmax){ bmax = nd; bidx = tid*16 + j; }
      }
      unsigned long long key = ((unsigned long long)__float_as_uint(bmax) << 32)
                             | (unsigned long long)(0xFFFFFFFFu - (unsigned)bidx);
#pragma unroll
      for (int o = 32; o; o >>= 1){
        unsigned long long ok = __shfl_down(key, o, 64);
        if (ok > key) key = ok;
      }
      if (lane == 0) atomicMax(&keyslot[t], key);
      __syncthreads();
      const unsigned long long gk = keyslot[t];
      const unsigned gidx = 0xFFFFFFFFu - (unsigned)(gk & 0xFFFFFFFFu);
      const float* cp = base + (size_t)gidx*3;
      cx = cp[0]; cy = cp[1]; cz = cp[2];
    }
  } else if (bid < 1028){
    // ---------------- sp: x0 = agg @ sp_w.T + sp_b ----------------
    __shared__ float ag[4096];
    for (int i = tid; i < 4096; i += 1024) ag[i] = agg[i];
    __syncthreads();
    const int wv = tid >> 6, lane = tid & 63;
    const int rbase = ((bid - 4)*16 + wv)*8;
    for (int rr = 0; rr < 8; ++rr){
      const int row = rbase + rr;
      const float* wp = spw + (size_t)row*1024 + lane*4;
      const float4 w0 = *(const float4*)(wp      );
      const float4 wq1 = *(const float4*)(wp + 256);
      const float4 wq2 = *(const float4*)(wp + 512);
      const float4 wq3 = *(const float4*)(wp + 768);
      float acc[4];
#pragma unroll
      for (int bb = 0; bb < 4; ++bb){
        const float* gp = &ag[bb*1024 + lane*4];
        const float4 g0 = *(const float4*)(gp      );
        const float4 g1 = *(const float4*)(gp + 256);
        const float4 g2 = *(const float4*)(gp + 512);
        const float4 g3 = *(const float4*)(gp + 768);
        acc[bb] = w0.x*g0.x + w0.y*g0.y + w0.z*g0.z + w0.w*g0.w
                + wq1.x*g1.x + wq1.y*g1.y + wq1.z*g1.z + wq1.w*g1.w
                + wq2.x*g2.x + wq2.y*g2.y + wq2.z*g2.z + wq2.w*g2.w
                + wq3.x*g3.x + wq3.y*g3.y + wq3.z*g3.z + wq3.w*g3.w;
      }
      float a0 = wredsum(acc[0]);
      float a1 = wredsum(acc[1]);
      float a2 = wredsum(acc[2]);
      float a3 = wredsum(acc[3]);
      if (lane == 0){
        const float bias = spb[row];
        x[(size_t)0*131072 + row] = a0 + bias;
        x[(size_t)1*131072 + row] = a1 + bias;
        x[(size_t)2*131072 + row] = a2 + bias;
        x[(size_t)3*131072 + row] = a3 + bias;
      }
    }
  } else {
    // ---------------- weight fp32 -> bf16 (all 4 layers + c1) ----------------
    const size_t t = (size_t)(bid - 1028)*1024 + tid;   // exactly 6272*1024 chunks
    const size_t i = t*8;
    const float* src;
    if (i < 50331648){
      const size_t l = i / 12582912, r = i - l*12582912;
      if (r < 3145728)       src = inw  + l*3145728 + r;
      else if (r < 4194304)  src = outw + l*1048576 + (r-3145728);
      else if (r < 8388608)  src = w1   + l*4194304 + (r-4194304);
      else                   src = w2   + l*4194304 + (r-8388608);
    } else src = c1w + (i - 50331648);
    float4 a = *(const float4*)src, bq = *(const float4*)(src+4);
    *(bf16x8_t*)(wbf + i) = pack8(a, bq);
  }
}

// ------------------------------------------------- mean over S (2-stage)
__global__ __launch_bounds__(256) void partial_kernel(const float* __restrict__ lh,
                                                      float* __restrict__ part){
  const int ph = blockIdx.x*256 + threadIdx.x;
  const int sc = blockIdx.y, b = blockIdx.z;
  const float* p = lh + ((size_t)b*512 + sc*64)*4096 + ph;
  float s0=0,s1=0,s2=0,s3=0;
  for (int j = 0; j < 64; j += 4){
    s0 += p[(size_t)(j+0)*4096];
    s1 += p[(size_t)(j+1)*4096];
    s2 += p[(size_t)(j+2)*4096];
    s3 += p[(size_t)(j+3)*4096];
  }
  part[(size_t)(b*8+sc)*4096 + ph] = (s0+s1)+(s2+s3);
}

__global__ __launch_bounds__(256) void combine_kernel(const float* __restrict__ part,
                                                      float* __restrict__ mlh){
  const int i = blockIdx.x*256 + threadIdx.x;
  const int b = i >> 12, ph = i & 4095;
  float s = 0;
#pragma unroll
  for (int sc = 0; sc < 8; ++sc) s += part[(size_t)(b*8+sc)*4096 + ph];
  mlh[i] = s * (1.0f/512.0f);
}

// ------------------------------------------------- agg = mean_lh @ fp_w.T + fp_b
__global__ __launch_bounds__(256) void agg_kernel(const float* __restrict__ mlh,
                                                  const float* __restrict__ fpw,
                                                  const float* __restrict__ fpb,
                                                  float* __restrict__ agg){
  const int o = blockIdx.x*4 + (threadIdx.x>>6);
  const int lane = threadIdx.x & 63;
  const int b = o >> 10, d = o & 1023;
  const float* mp = mlh + b*4096;
  const float* wp = fpw + (size_t)d*4096;
  float s = 0;
#pragma unroll 4
  for (int j = 0; j < 64; ++j){
    int ph = lane + j*64;
    s += mp[ph] * wp[ph];
  }
  s = wredsum(s);
  if (lane == 0) agg[o] = s + fpb[d];
}

// ------------------------------------------------- LayerNorm (optional +pos), bf16 out
__global__ __launch_bounds__(256) void ln_kernel(const float* __restrict__ x,
                                                 const float* __restrict__ pos,
                                                 const float* __restrict__ w,
                                                 const float* __restrict__ bb,
                                                 __bf16* __restrict__ out){
  const int tok = blockIdx.x, g = tok & 127, t = threadIdx.x;
  const int lane = t & 63, wv = t >> 6;
  const float* xr = x + (size_t)tok*1024;
  float v[4];
#pragma unroll
  for (int j = 0; j < 4; ++j){
    int d = t + j*256;
    float val = xr[d];
    if (pos) val += pos[g*1024 + d];
    v[j] = val;
  }
  __shared__ float r1[4], r2[4];
  float s = wredsum(v[0]+v[1]+v[2]+v[3]);
  if (lane == 0) r1[wv] = s;
  __syncthreads();
  const float mean = (r1[0]+r1[1]+r1[2]+r1[3]) * (1.0f/1024.0f);
  float sq = 0;
#pragma unroll
  for (int j = 0; j < 4; ++j){ float d0 = v[j]-mean; sq += d0*d0; }
  sq = wredsum(sq);
  if (lane == 0) r2[wv] = sq;
  __syncthreads();
  const float var = (r2[0]+r2[1]+r2[2]+r2[3]) * (1.0f/1024.0f);
  const float rs = rsqrtf(var + 1e-5f);
#pragma unroll
  for (int j = 0; j < 4; ++j){
    int d = t + j*256;
    out[(size_t)tok*1024 + d] = (__bf16)((v[j]-mean)*rs*w[d] + bb[d]);
  }
}

// ------------------------------------------------- bf16 MFMA split-K GEMM, 128x128 tile
__global__ __launch_bounds__(256) void gemm_sk(
  const __bf16* __restrict__ A, const __bf16* __restrict__ W,
  float* __restrict__ parts, int M, int N, int K, int kc)
{
  __shared__ __bf16 As[128*32];
  __shared__ __bf16 Ws[128*32];
  const int n0 = blockIdx.x*128, m0 = blockIdx.y*128, z = blockIdx.z;
  const int tid = threadIdx.x;
  const int lane = tid & 63, w = tid >> 6;
  const int wm = w >> 1, wn = w & 1;
  const int lr = lane & 15, g = lane >> 4;
  const int kbeg = z*kc, kend = kbeg + kc;
  f32x4_t acc[4][4] = {};
  for (int k0 = kbeg; k0 < kend; k0 += 32){
    __syncthreads();
#pragma unroll
    for (int i = 0; i < 2; ++i){
      const int c = tid + i*256;          // chunk 0..511: row=c>>2, quarter=c&3
      const int row = c >> 2, q = c & 3;
      gload16(A + (size_t)(m0+row)*K + k0 + q*8, &As[(size_t)c*8]);
      gload16(W + (size_t)(n0+row)*K + k0 + q*8, &Ws[(size_t)c*8]);
    }
    __syncthreads();
    bf16x8_t af[4], bf[4];
#pragma unroll
    for (int f = 0; f < 4; ++f){
      af[f] = *(bf16x8_t*)&As[(wm*64 + f*16 + lr)*32 + g*8];
      bf[f] = *(bf16x8_t*)&Ws[(wn*64 + f*16 + lr)*32 + g*8];
    }
#pragma unroll
    for (int i = 0; i < 4; ++i)
#pragma unroll
      for (int j = 0; j < 4; ++j)
        acc[i][j] = __builtin_amdgcn_mfma_f32_16x16x32_bf16(af[i], bf[j], acc[i][j], 0, 0, 0);
  }
  float* C = parts + (size_t)z*M*N;
#pragma unroll
  for (int i = 0; i < 4; ++i)
#pragma unroll
    for (int j = 0; j < 4; ++j)
#pragma unroll
      for (int r = 0; r < 4; ++r){
        const int row = m0 + wm*64 + i*16 + g*4 + r;
        const int col = n0 + wn*64 + j*16 + lr;
        C[(size_t)row*N + col] = acc[i][j][r];
      }
}

// ------------------------------------------------- combines
__global__ __launch_bounds__(256) void comb_gelu(const float* __restrict__ parts,
                                                 const float* __restrict__ bias,
                                                 __bf16* __restrict__ out){
  const int i = blockIdx.x*256 + threadIdx.x;   // < 2097152
  const int col = i & 4095;
  float v = parts[i] + parts[2097152 + i] + bias[col];
  v = v * 0.5f * (1.0f + erff(v * 0.70710678118654752440f));
  out[i] = (__bf16)v;
}

// residual add (+bias, nsplit fp32 partials) into x, then optional LayerNorm -> bf16 xn.
// MODE 0: LN; MODE 1: LN with pos added to LN input; MODE 2: no LN, emit bf16 copy of x.
template<int MODE>
__global__ __launch_bounds__(256) void comb_res_ln(const float* __restrict__ parts, int nsplit,
                                                   const float* __restrict__ bias,
                                                   const float* __restrict__ pos,
                                                   const float* __restrict__ lw,
                                                   const float* __restrict__ lb,
                                                   float* __restrict__ x,
                                                   __bf16* __restrict__ xn){
  const int tok = blockIdx.x, gi = tok & 127, t = threadIdx.x;
  const int lane = t & 63, wv = t >> 6;
  float v[4];
#pragma unroll
  for (int j = 0; j < 4; ++j){
    const int d = t + j*256;
    const size_t idx = (size_t)tok*1024 + d;
    float s = 0;
    for (int z = 0; z < nsplit; ++z) s += parts[(size_t)z*524288 + idx];
    float val = x[idx] + s + bias[d];
    x[idx] = val;
    v[j] = val;
  }
  if (MODE == 2){
#pragma unroll
    for (int j = 0; j < 4; ++j){
      const int d = t + j*256;
      xn[(size_t)tok*1024 + d] = (__bf16)v[j];
    }
    return;
  }
  float u[4];
#pragma unroll
  for (int j = 0; j < 4; ++j){
    const int d = t + j*256;
    u[j] = v[j] + (MODE == 1 ? pos[gi*1024 + d] : 0.0f);
  }
  __shared__ float r1[4], r2[4];
  float s1 = wredsum(u[0]+u[1]+u[2]+u[3]);
  if (lane == 0) r1[wv] = s1;
  __syncthreads();
  const float mean = (r1[0]+r1[1]+r1[2]+r1[3]) * (1.0f/1024.0f);
  float sq = 0;
#pragma unroll
  for (int j = 0; j < 4; ++j){ float d0 = u[j]-mean; sq += d0*d0; }
  sq = wredsum(sq);
  if (lane == 0) r2[wv] = sq;
  __syncthreads();
  const float var = (r2[0]+r2[1]+r2[2]+r2[3]) * (1.0f/1024.0f);
  const float rs = rsqrtf(var + 1e-5f);
#pragma unroll
  for (int j = 0; j < 4; ++j){
    const int d = t + j*256;
    xn[(size_t)tok*1024 + d] = (__bf16)((u[j]-mean)*rs*lw[d] + lb[d]);
  }
}

// ------------------------------------------------- fused attention v3: reads qkv split-2 partials
// one block per (b,h,half); identical math to v2 (same (__bf16)(p0+p1+bias) rounding).
__global__ __launch_bounds__(256) void attn_fused(const float* __restrict__ p0,
                                                  const float* __restrict__ p1,
                                                  const float* __restrict__ bias,
                                                  __bf16* __restrict__ O){
  const int bh = blockIdx.x >> 1, half = blockIdx.x & 1;
  const int b = bh>>3, h = bh&7;
  const int tid = threadIdx.x, w = tid>>6, lane = tid&63;
  const int lr = lane&15, g = lane>>4;
  __shared__ __bf16 vt[128*128];    // V^T swizzled
  __shared__ __bf16 pl[4*2048];     // per-wave P (16x128), swizzled
  {
    const int n = tid >> 1, kh = tid & 1;
    const size_t vb0 = (size_t)(b*128)*3072 + 2048 + h*128 + n;
    const float vbias = bias[2048 + h*128 + n];
#pragma unroll
    for (int jb = 0; jb < 8; ++jb){
      bf16x8_t pk;
#pragma unroll
      for (int e = 0; e < 8; ++e){
        const size_t off = vb0 + (size_t)(kh*64 + jb*8 + e)*3072;
        pk[e] = (__bf16)(p0[off] + p1[off] + vbias);
      }
      const int cb = kh*8 + jb;
      *(bf16x8_t*)&vt[n*128 + ((cb ^ (n&7)) * 8)] = pk;
    }
  }
  const int qrow0 = half*64 + w*16;
  f32x4_t acc[8] = {};
#pragma unroll
  for (int ks = 0; ks < 4; ++ks){
    bf16x8_t aq, bk[8];
    {
      const int cq = h*128 + ks*32 + g*8;
      const size_t idx = (size_t)(b*128 + qrow0 + lr)*3072 + cq;
      const float4 a0 = *(const float4*)(p0+idx), a1 = *(const float4*)(p0+idx+4);
      const float4 b0 = *(const float4*)(p1+idx), b1 = *(const float4*)(p1+idx+4);
      const float4 c0 = *(const float4*)(bias+cq), c1 = *(const float4*)(bias+cq+4);
      float4 lo, hi;
      lo.x=a0.x+b0.x+c0.x; lo.y=a0.y+b0.y+c0.y; lo.z=a0.z+b0.z+c0.z; lo.w=a0.w+b0.w+c0.w;
      hi.x=a1.x+b1.x+c1.x; hi.y=a1.y+b1.y+c1.y; hi.z=a1.z+b1.z+c1.z; hi.w=a1.w+b1.w+c1.w;
      aq = pack8(lo, hi);
    }
#pragma unroll
    for (int j = 0; j < 8; ++j){
      const int ck = 1024 + h*128 + ks*32 + g*8;
      const size_t idx = (size_t)(b*128 + j*16 + lr)*3072 + ck;
      const float4 a0 = *(const float4*)(p0+idx), a1 = *(const float4*)(p0+idx+4);
      const float4 b0 = *(const float4*)(p1+idx), b1 = *(const float4*)(p1+idx+4);
      const float4 c0 = *(const float4*)(bias+ck), c1 = *(const float4*)(bias+ck+4);
      float4 lo, hi;
      lo.x=a0.x+b0.x+c0.x; lo.y=a0.y+b0.y+c0.y; lo.z=a0.z+b0.z+c0.z; lo.w=a0.w+b0.w+c0.w;
      hi.x=a1.x+b1.x+c1.x; hi.y=a1.y+b1.y+c1.y; hi.z=a1.z+b1.z+c1.z; hi.w=a1.w+b1.w+c1.w;
      bk[j] = pack8(lo, hi);
    }
#pragma unroll
    for (int j = 0; j < 8; ++j)
      acc[j] = __builtin_amdgcn_mfma_f32_16x16x32_bf16(aq, bk[j], acc[j], 0, 0, 0);
  }
  __syncthreads();
  const float scale = 0.088388347648318447f;  // 1/sqrt(128)
#pragma unroll
  for (int r = 0; r < 4; ++r){
    const int row = g*4 + r;
    float sv[8];
    float mx = -1e30f;
#pragma unroll
    for (int j = 0; j < 8; ++j){ sv[j] = acc[j][r]*scale; mx = fmaxf(mx, sv[j]); }
#pragma unroll
    for (int o = 1; o < 16; o <<= 1) mx = fmaxf(mx, __shfl_xor(mx, o, 64));
    float s = 0;
#pragma unroll
    for (int j = 0; j < 8; ++j){ sv[j] = expf(sv[j]-mx); s += sv[j]; }
#pragma unroll
    for (int o = 1; o < 16; o <<= 1) s += __shfl_xor(s, o, 64);
    const float inv = 1.0f/s;
#pragma unroll
    for (int j = 0; j < 8; ++j){
      const int col = j*16 + lr;
      const int slot = (col>>3) ^ (row&7);
      pl[w*2048 + row*128 + slot*8 + (lr&7)] = (__bf16)(sv[j]*inv);
    }
  }
  __syncthreads();
  f32x4_t acc2[8] = {};
#pragma unroll
  for (int ks = 0; ks < 4; ++ks){
    bf16x8_t ap, bv[8];
    {
      const int row = lr;
      const int slot = (ks*4 + g) ^ (row&7);
      ap = *(bf16x8_t*)&pl[w*2048 + row*128 + slot*8];
    }
#pragma unroll
    for (int j = 0; j < 8; ++j){
      const int rowv = j*16 + lr;
      const int cb = ks*4 + g;
      bv[j] = *(bf16x8_t*)&vt[rowv*128 + ((cb ^ (rowv&7))*8)];
    }
#pragma unroll
    for (int j = 0; j < 8; ++j)
      acc2[j] = __builtin_amdgcn_mfma_f32_16x16x32_bf16(ap, bv[j], acc2[j], 0, 0, 0);
  }
#pragma unroll
  for (int j = 0; j < 8; ++j)
#pragma unroll
    for (int r = 0; r < 4; ++r){
      const int row = qrow0 + g*4 + r;
      const int col = j*16 + lr;
      O[(size_t)(b*128+row)*1024 + h*128 + col] = (__bf16)acc2[j][r];
    }
}

// ------------------------------------------------- head: c1 combine + BN + ReLU + c2 GEMV + centers
// one block per token (512 blocks). hc1 row built in LDS, then 96 wave-dots.
__global__ __launch_bounds__(256) void head_kernel(const float* __restrict__ parts,
                                                   const float* __restrict__ c1b,
                                                   const float* __restrict__ bnm,
                                                   const float* __restrict__ bnv,
                                                   const float* __restrict__ bng,
                                                   const float* __restrict__ bnb,
                                                   const float* __restrict__ c2w,
                                                   const float* __restrict__ c2b,
                                                   const float* __restrict__ centers,
                                                   float* __restrict__ out){
  const int tok = blockIdx.x, t = threadIdx.x;
  const int wv = t >> 6, lane = t & 63;
  __shared__ float hrow[1024];
#pragma unroll
  for (int j = 0; j < 4; ++j){
    const int d = t + j*256;
    const size_t idx = (size_t)tok*1024 + d;
    float s = 0;
#pragma unroll
    for (int z = 0; z < 8; ++z) s += parts[(size_t)z*524288 + idx];
    float v = s + c1b[d];
    v = (v - bnm[d]) * rsqrtf(bnv[d] + 1e-5f) * bng[d] + bnb[d];
    hrow[d] = fmaxf(v, 0.0f);
  }
  __syncthreads();
  for (int i = 0; i < 24; ++i){
    const int n = wv*24 + i;
    const float* wp = c2w + (size_t)n*1024;
    float s = 0;
#pragma unroll 4
    for (int j = 0; j < 16; ++j){
      const int k = lane + j*64;
      s += hrow[k] * wp[k];
    }
    s = wredsum(s);
    if (lane == 0) out[(size_t)tok*96 + n] = s + c2b[n] + centers[tok*3 + (n % 3)];
  }
}

// =================================================================
extern "C" void kernel_launch(void* const* d_in, const int* in_sizes, int n_in,
                              void* d_out, int out_size, void* d_ws, size_t ws_size,
                              hipStream_t stream){
  const float* lh   = (const float*)d_in[0];
  const float* pc   = (const float*)d_in[1];
  const float* fpw  = (const float*)d_in[2];
  const float* fpb  = (const float*)d_in[3];
  const float* spw  = (const float*)d_in[4];
  const float* spb  = (const float*)d_in[5];
  const float* pos  = (const float*)d_in[6];
  const float* ln1w = (const float*)d_in[7];
  const float* ln1b = (const float*)d_in[8];
  const float* inw  = (const float*)d_in[9];
  const float* inb  = (const float*)d_in[10];
  const float* outw = (const float*)d_in[11];
  const float* outb = (const float*)d_in[12];
  const float* ln2w = (const float*)d_in[13];
  const float* ln2b = (const float*)d_in[14];
  const float* w1   = (const float*)d_in[15];
  const float* b1   = (const float*)d_in[16];
  const float* w2   = (const float*)d_in[17];
  const float* b2   = (const float*)d_in[18];
  const float* c1w  = (const float*)d_in[19];
  const float* c1b  = (const float*)d_in[20];
  const float* bng  = (const float*)d_in[21];
  const float* bnbt = (const float*)d_in[22];
  const float* bnm  = (const float*)d_in[23];
  const float* bnv  = (const float*)d_in[24];
  const float* c2w  = (const float*)d_in[25];
  const float* c2b  = (const float*)d_in[26];
  float* out = (float*)d_out;

  // ---- workspace layout ----
  float* f = (float*)d_ws;
  float* parts = f;              f += 16*524288;  // split-K fp32 partials (32 MB)
  float* part  = f;              f += 131072;
  float* mlh   = f;              f += 16384;
  float* agg   = f;              f += 4096;
  float* x     = f;              f += 524288;     // residual stream fp32
  float* cent  = f;              f += 2048;       // centers (+pad)
  __bf16* bfp = (__bf16*)f;
  __bf16* xn   = bfp;            bfp += 524288;   // LN out bf16
  __bf16* obuf = bfp;            bfp += 524288;
  __bf16* hbf  = bfp;            bfp += 2097152;  // MLP hidden bf16
  __bf16* xbf  = bfp;            bfp += 524288;   // bf16 copy of final x
  __bf16* wbf  = bfp;            bfp += 51380224; // all weights bf16 (4 layers + c1 at +50331648)

  partial_kernel<<<dim3(16,8,4), 256, 0, stream>>>(lh, part);
  combine_kernel<<<64, 256, 0, stream>>>(part, mlh);
  agg_kernel<<<1024, 256, 0, stream>>>(mlh, fpw, fpb, agg);
  fused_front<<<7300, 1024, 0, stream>>>(pc, cent, agg, spw, spb, x,
                                         inw, outw, w1, w2, c1w, wbf);
  ln_kernel<<<512, 256, 0, stream>>>(x, pos, ln1w, ln1b, xn);

  for (int l = 0; l < 4; ++l){
    const __bf16* wl = wbf + (size_t)l*12582912;
    // qkv: 512x3072x1024, split-2 (192 blocks); attn consumes the 2 partials directly
    gemm_sk<<<dim3(24,4,2), 256, 0, stream>>>(xn, wl, parts, 512, 3072, 1024, 512);
    attn_fused<<<64, 256, 0, stream>>>(parts, parts + 1572864, inb + l*3072, obuf);
    // attn-out: 512x1024x1024, split-8 (256 blocks)
    gemm_sk<<<dim3(8,4,8), 256, 0, stream>>>(obuf, wl + 3145728, parts, 512, 1024, 1024, 128);
    comb_res_ln<0><<<512, 256, 0, stream>>>(parts, 8, outb + l*1024, nullptr,
                                            ln2w + l*1024, ln2b + l*1024, x, xn);
    // mlp1: 512x4096x1024, split-2 (256 blocks)
    gemm_sk<<<dim3(32,4,2), 256, 0, stream>>>(xn, wl + 4194304, parts, 512, 4096, 1024, 512);
    comb_gelu<<<8192, 256, 0, stream>>>(parts, b1 + l*4096, hbf);
    // mlp2: 512x1024x4096, split-8 (256 blocks)
    gemm_sk<<<dim3(8,4,8), 256, 0, stream>>>(hbf, wl + 8388608, parts, 512, 1024, 4096, 512);
    if (l < 3)
      comb_res_ln<1><<<512, 256, 0, stream>>>(parts, 8, b2 + l*1024, pos,
                                              ln1w + (l+1)*1024, ln1b + (l+1)*1024, x, xn);
    else
      comb_res_ln<2><<<512, 256, 0, stream>>>(parts, 8, b2 + l*1024, nullptr,
                                              nullptr, nullptr, x, xbf);
  }

  // c1: 512x1024x1024, split-8 (256 blocks); head fuses combine+BN+ReLU+c2+centers
  gemm_sk<<<dim3(8,4,8), 256, 0, stream>>>(xbf, wbf + 50331648, parts, 512, 1024, 1024, 128);
  head_kernel<<<512, 256, 0, stream>>>(parts, c1b, bnm, bnv, bng, bnbt, c2w, c2b, cent, out);
}

// Round 9
// 825.368 us; speedup vs baseline: 1.2962x; 1.0572x over previous
//
#include <hip/hip_runtime.h>
#include <hip/hip_bf16.h>
#include <math.h>

// Shapes (fixed): B=4, S=512, PH=4096, N=16384, D=1024, G=128, H=8, L=4, FF=4096, GS=32, HD=128

typedef __bf16 bf16x8_t __attribute__((ext_vector_type(8)));
typedef float  f32x4_t  __attribute__((ext_vector_type(4)));

__device__ __forceinline__ float wredsum(float v){
#pragma unroll
  for (int o = 32; o; o >>= 1) v += __shfl_down(v, o, 64);
  return v;  // valid in lane 0
}

__device__ __forceinline__ bf16x8_t pack8(float4 a, float4 b){
  bf16x8_t v;
  v[0]=(__bf16)a.x; v[1]=(__bf16)a.y; v[2]=(__bf16)a.z; v[3]=(__bf16)a.w;
  v[4]=(__bf16)b.x; v[5]=(__bf16)b.y; v[6]=(__bf16)b.z; v[7]=(__bf16)b.w;
  return v;
}

__device__ __forceinline__ void gload16(const void* g, void* l){
  __builtin_amdgcn_global_load_lds((const __attribute__((address_space(1))) unsigned int*)g,
                                   (__attribute__((address_space(3))) unsigned int*)l, 16, 0, 0);
}

// ---------------------------------------------------------------- fused front-end
// blocks 0..3: FPS; 4..1027: sp GEMV (537 MB); 1028..7299: weight fp32->bf16 (308 MB)
__global__ __launch_bounds__(1024) void fused_front(
  const float* __restrict__ pc, float* __restrict__ centers,
  const float* __restrict__ agg, const float* __restrict__ spw,
  const float* __restrict__ spb, float* __restrict__ x,
  const float* __restrict__ inw, const float* __restrict__ outw,
  const float* __restrict__ w1, const float* __restrict__ w2,
  const float* __restrict__ c1w, __bf16* __restrict__ wbf)
{
  const int bid = blockIdx.x;
  const int tid = threadIdx.x;
  if (bid < 4){
    // ---------------- FPS v3 (validated) ----------------
    const int b = bid;
    const int lane = tid & 63;
    const float* base = pc + (size_t)b * 16384 * 3;
    float px[16], py[16], pz[16], dist[16];
    {
      union { float4 v4[12]; float f[48]; } u;
      const float4* src = (const float4*)(base + tid * 48);
#pragma unroll
      for (int q = 0; q < 12; ++q) u.v4[q] = src[q];
#pragma unroll
      for (int j = 0; j < 16; ++j){
        px[j] = u.f[j*3]; py[j] = u.f[j*3+1]; pz[j] = u.f[j*3+2];
        dist[j] = 1e10f;
      }
    }
    __shared__ unsigned long long keyslot[128];
    for (int i = tid; i < 128; i += 1024) keyslot[i] = 0ULL;
    __syncthreads();
    float cx = base[0], cy = base[1], cz = base[2];
    for (int t = 0; t < 128; ++t){
      if (tid == 0){
        centers[(b*128+t)*3+0] = cx;
        centers[(b*128+t)*3+1] = cy;
        centers[(b*128+t)*3+2] = cz;
      }
      if (t == 127) break;
      float bmax = -1.0f; int bidx = 0;
#pragma unroll
      for (int j = 0; j < 16; ++j){
        float dx = __fsub_rn(px[j], cx);
        float dy = __fsub_rn(py[j], cy);
        float dz = __fsub_rn(pz[j], cz);
        float d  = __fadd_rn(__fadd_rn(__fmul_rn(dx,dx), __fmul_rn(dy,dy)), __fmul_rn(dz,dz));
        float nd = fminf(dist[j], d);
        dist[j] = nd;
        if (nd > bmax){ bmax = nd; bidx = tid*16 + j; }
      }
      unsigned long long key = ((unsigned long long)__float_as_uint(bmax) << 32)
                             | (unsigned long long)(0xFFFFFFFFu - (unsigned)bidx);
#pragma unroll
      for (int o = 32; o; o >>= 1){
        unsigned long long ok = __shfl_down(key, o, 64);
        if (ok > key) key = ok;
      }
      if (lane == 0) atomicMax(&keyslot[t], key);
      __syncthreads();
      const unsigned long long gk = keyslot[t];
      const unsigned gidx = 0xFFFFFFFFu - (unsigned)(gk & 0xFFFFFFFFu);
      const float* cp = base + (size_t)gidx*3;
      cx = cp[0]; cy = cp[1]; cz = cp[2];
    }
  } else if (bid < 1028){
    // ---------------- sp: x0 = agg @ sp_w.T + sp_b ----------------
    __shared__ float ag[4096];
    for (int i = tid; i < 4096; i += 1024) ag[i] = agg[i];
    __syncthreads();
    const int wv = tid >> 6, lane = tid & 63;
    const int rbase = ((bid - 4)*16 + wv)*8;
    for (int rr = 0; rr < 8; ++rr){
      const int row = rbase + rr;
      const float* wp = spw + (size_t)row*1024 + lane*4;
      const float4 w0 = *(const float4*)(wp      );
      const float4 wq1 = *(const float4*)(wp + 256);
      const float4 wq2 = *(const float4*)(wp + 512);
      const float4 wq3 = *(const float4*)(wp + 768);
      float acc[4];
#pragma unroll
      for (int bb = 0; bb < 4; ++bb){
        const float* gp = &ag[bb*1024 + lane*4];
        const float4 g0 = *(const float4*)(gp      );
        const float4 g1 = *(const float4*)(gp + 256);
        const float4 g2 = *(const float4*)(gp + 512);
        const float4 g3 = *(const float4*)(gp + 768);
        acc[bb] = w0.x*g0.x + w0.y*g0.y + w0.z*g0.z + w0.w*g0.w
                + wq1.x*g1.x + wq1.y*g1.y + wq1.z*g1.z + wq1.w*g1.w
                + wq2.x*g2.x + wq2.y*g2.y + wq2.z*g2.z + wq2.w*g2.w
                + wq3.x*g3.x + wq3.y*g3.y + wq3.z*g3.z + wq3.w*g3.w;
      }
      float a0 = wredsum(acc[0]);
      float a1 = wredsum(acc[1]);
      float a2 = wredsum(acc[2]);
      float a3 = wredsum(acc[3]);
      if (lane == 0){
        const float bias = spb[row];
        x[(size_t)0*131072 + row] = a0 + bias;
        x[(size_t)1*131072 + row] = a1 + bias;
        x[(size_t)2*131072 + row] = a2 + bias;
        x[(size_t)3*131072 + row] = a3 + bias;
      }
    }
  } else {
    // ---------------- weight fp32 -> bf16 (all 4 layers + c1) ----------------
    const size_t t = (size_t)(bid - 1028)*1024 + tid;   // exactly 6272*1024 chunks
    const size_t i = t*8;
    const float* src;
    if (i < 50331648){
      const size_t l = i / 12582912, r = i - l*12582912;
      if (r < 3145728)       src = inw  + l*3145728 + r;
      else if (r < 4194304)  src = outw + l*1048576 + (r-3145728);
      else if (r < 8388608)  src = w1   + l*4194304 + (r-4194304);
      else                   src = w2   + l*4194304 + (r-8388608);
    } else src = c1w + (i - 50331648);
    float4 a = *(const float4*)src, bq = *(const float4*)(src+4);
    *(bf16x8_t*)(wbf + i) = pack8(a, bq);
  }
}

// ------------------------------------------------- mean over S (2-stage)
__global__ __launch_bounds__(256) void partial_kernel(const float* __restrict__ lh,
                                                      float* __restrict__ part){
  const int ph = blockIdx.x*256 + threadIdx.x;
  const int sc = blockIdx.y, b = blockIdx.z;
  const float* p = lh + ((size_t)b*512 + sc*64)*4096 + ph;
  float s0=0,s1=0,s2=0,s3=0;
  for (int j = 0; j < 64; j += 4){
    s0 += p[(size_t)(j+0)*4096];
    s1 += p[(size_t)(j+1)*4096];
    s2 += p[(size_t)(j+2)*4096];
    s3 += p[(size_t)(j+3)*4096];
  }
  part[(size_t)(b*8+sc)*4096 + ph] = (s0+s1)+(s2+s3);
}

__global__ __launch_bounds__(256) void combine_kernel(const float* __restrict__ part,
                                                      float* __restrict__ mlh){
  const int i = blockIdx.x*256 + threadIdx.x;
  const int b = i >> 12, ph = i & 4095;
  float s = 0;
#pragma unroll
  for (int sc = 0; sc < 8; ++sc) s += part[(size_t)(b*8+sc)*4096 + ph];
  mlh[i] = s * (1.0f/512.0f);
}

// ------------------------------------------------- agg = mean_lh @ fp_w.T + fp_b
__global__ __launch_bounds__(256) void agg_kernel(const float* __restrict__ mlh,
                                                  const float* __restrict__ fpw,
                                                  const float* __restrict__ fpb,
                                                  float* __restrict__ agg){
  const int o = blockIdx.x*4 + (threadIdx.x>>6);
  const int lane = threadIdx.x & 63;
  const int b = o >> 10, d = o & 1023;
  const float* mp = mlh + b*4096;
  const float* wp = fpw + (size_t)d*4096;
  float s = 0;
#pragma unroll 4
  for (int j = 0; j < 64; ++j){
    int ph = lane + j*64;
    s += mp[ph] * wp[ph];
  }
  s = wredsum(s);
  if (lane == 0) agg[o] = s + fpb[d];
}

// ------------------------------------------------- LayerNorm (optional +pos), bf16 out
__global__ __launch_bounds__(256) void ln_kernel(const float* __restrict__ x,
                                                 const float* __restrict__ pos,
                                                 const float* __restrict__ w,
                                                 const float* __restrict__ bb,
                                                 __bf16* __restrict__ out){
  const int tok = blockIdx.x, g = tok & 127, t = threadIdx.x;
  const int lane = t & 63, wv = t >> 6;
  const float* xr = x + (size_t)tok*1024;
  float v[4];
#pragma unroll
  for (int j = 0; j < 4; ++j){
    int d = t + j*256;
    float val = xr[d];
    if (pos) val += pos[g*1024 + d];
    v[j] = val;
  }
  __shared__ float r1[4], r2[4];
  float s = wredsum(v[0]+v[1]+v[2]+v[3]);
  if (lane == 0) r1[wv] = s;
  __syncthreads();
  const float mean = (r1[0]+r1[1]+r1[2]+r1[3]) * (1.0f/1024.0f);
  float sq = 0;
#pragma unroll
  for (int j = 0; j < 4; ++j){ float d0 = v[j]-mean; sq += d0*d0; }
  sq = wredsum(sq);
  if (lane == 0) r2[wv] = sq;
  __syncthreads();
  const float var = (r2[0]+r2[1]+r2[2]+r2[3]) * (1.0f/1024.0f);
  const float rs = rsqrtf(var + 1e-5f);
#pragma unroll
  for (int j = 0; j < 4; ++j){
    int d = t + j*256;
    out[(size_t)tok*1024 + d] = (__bf16)((v[j]-mean)*rs*w[d] + bb[d]);
  }
}

// ------------------------------------------------- bf16 MFMA split-K GEMM, 128x128 tile
// 4-deep pipelined staging with counted vmcnt (T3/T4): prologue stages tiles 0..2;
// per iter t: vmcnt(8) [tile t = loads 4t..4t+3 of 4t+12 issued -> exactly retires
// tile t], raw s_barrier [also guarantees all waves consumed buf (t-1)&3, the buffer
// tile t+3 overwrites], stage tile t+3 (clamped at tail; lands in a buffer that is
// never read again), ds_read buf t&3 + 16 MFMA. Requires kc >= 128 (nst >= 4).
__global__ __launch_bounds__(256) void gemm_sk(
  const __bf16* __restrict__ A, const __bf16* __restrict__ W,
  float* __restrict__ parts, int M, int N, int K, int kc)
{
  __shared__ __bf16 As[4][128*32];
  __shared__ __bf16 Ws[4][128*32];
  const int n0 = blockIdx.x*128, m0 = blockIdx.y*128, z = blockIdx.z;
  const int tid = threadIdx.x;
  const int lane = tid & 63, w = tid >> 6;
  const int wm = w >> 1, wn = w & 1;
  const int lr = lane & 15, g = lane >> 4;
  const int kbeg = z*kc;
  const int nst = kc >> 5;
  const int c0 = tid, c1 = tid + 256;          // chunk: row=c>>2, quarter=c&3
  const int r0 = c0 >> 2, q0 = c0 & 3;
  const int r1 = c1 >> 2, q1 = c1 & 3;
  const __bf16* a0 = A + (size_t)(m0 + r0)*K + kbeg + q0*8;
  const __bf16* a1 = A + (size_t)(m0 + r1)*K + kbeg + q1*8;
  const __bf16* w0 = W + (size_t)(n0 + r0)*K + kbeg + q0*8;
  const __bf16* w1 = W + (size_t)(n0 + r1)*K + kbeg + q1*8;

#define STAGE(BUF, KOFF) do { \
    gload16(a0 + (KOFF), &As[(BUF)][c0*8]); \
    gload16(a1 + (KOFF), &As[(BUF)][c1*8]); \
    gload16(w0 + (KOFF), &Ws[(BUF)][c0*8]); \
    gload16(w1 + (KOFF), &Ws[(BUF)][c1*8]); \
  } while(0)

  STAGE(0, 0);
  STAGE(1, 32);
  STAGE(2, 64);
  f32x4_t acc[4][4] = {};
  for (int t = 0; t < nst; ++t){
    asm volatile("s_waitcnt vmcnt(8)" ::: "memory");
    __builtin_amdgcn_s_barrier();
    const int tnext = (t+3 < nst) ? (t+3) : (nst-1);   // clamped tail restage
    STAGE((t+3)&3, tnext*32);
    const int cb = t & 3;
    bf16x8_t af[4], bf[4];
#pragma unroll
    for (int f = 0; f < 4; ++f){
      af[f] = *(bf16x8_t*)&As[cb][(wm*64 + f*16 + lr)*32 + g*8];
      bf[f] = *(bf16x8_t*)&Ws[cb][(wn*64 + f*16 + lr)*32 + g*8];
    }
#pragma unroll
    for (int i = 0; i < 4; ++i)
#pragma unroll
      for (int j = 0; j < 4; ++j)
        acc[i][j] = __builtin_amdgcn_mfma_f32_16x16x32_bf16(af[i], bf[j], acc[i][j], 0, 0, 0);
  }
#undef STAGE
  float* C = parts + (size_t)z*M*N;
#pragma unroll
  for (int i = 0; i < 4; ++i)
#pragma unroll
    for (int j = 0; j < 4; ++j)
#pragma unroll
      for (int r = 0; r < 4; ++r){
        const int row = m0 + wm*64 + i*16 + g*4 + r;
        const int col = n0 + wn*64 + j*16 + lr;
        C[(size_t)row*N + col] = acc[i][j][r];
      }
}

// ------------------------------------------------- combines (2-split versions, validated K5)
__global__ __launch_bounds__(256) void comb_qkv(const float* __restrict__ parts,
                                                const float* __restrict__ bias,
                                                __bf16* __restrict__ out){
  const int i = blockIdx.x*256 + threadIdx.x;   // < 1572864
  const int col = i % 3072;
  out[i] = (__bf16)(parts[i] + parts[1572864 + i] + bias[col]);
}

__global__ __launch_bounds__(256) void comb_gelu(const float* __restrict__ parts,
                                                 const float* __restrict__ bias,
                                                 __bf16* __restrict__ out){
  const int i = blockIdx.x*256 + threadIdx.x;   // < 2097152
  const int col = i & 4095;
  float v = parts[i] + parts[2097152 + i] + bias[col];
  v = v * 0.5f * (1.0f + erff(v * 0.70710678118654752440f));
  out[i] = (__bf16)v;
}

// residual add (+bias, nsplit fp32 partials) into x, then optional LayerNorm -> bf16 xn.
// MODE 0: LN; MODE 1: LN with pos added to LN input; MODE 2: no LN, emit bf16 copy of x.
template<int MODE>
__global__ __launch_bounds__(256) void comb_res_ln(const float* __restrict__ parts, int nsplit,
                                                   const float* __restrict__ bias,
                                                   const float* __restrict__ pos,
                                                   const float* __restrict__ lw,
                                                   const float* __restrict__ lb,
                                                   float* __restrict__ x,
                                                   __bf16* __restrict__ xn){
  const int tok = blockIdx.x, gi = tok & 127, t = threadIdx.x;
  const int lane = t & 63, wv = t >> 6;
  float v[4];
#pragma unroll
  for (int j = 0; j < 4; ++j){
    const int d = t + j*256;
    const size_t idx = (size_t)tok*1024 + d;
    float s = 0;
    for (int z = 0; z < nsplit; ++z) s += parts[(size_t)z*524288 + idx];
    float val = x[idx] + s + bias[d];
    x[idx] = val;
    v[j] = val;
  }
  if (MODE == 2){
#pragma unroll
    for (int j = 0; j < 4; ++j){
      const int d = t + j*256;
      xn[(size_t)tok*1024 + d] = (__bf16)v[j];
    }
    return;
  }
  float u[4];
#pragma unroll
  for (int j = 0; j < 4; ++j){
    const int d = t + j*256;
    u[j] = v[j] + (MODE == 1 ? pos[gi*1024 + d] : 0.0f);
  }
  __shared__ float r1[4], r2[4];
  float s1 = wredsum(u[0]+u[1]+u[2]+u[3]);
  if (lane == 0) r1[wv] = s1;
  __syncthreads();
  const float mean = (r1[0]+r1[1]+r1[2]+r1[3]) * (1.0f/1024.0f);
  float sq = 0;
#pragma unroll
  for (int j = 0; j < 4; ++j){ float d0 = u[j]-mean; sq += d0*d0; }
  sq = wredsum(sq);
  if (lane == 0) r2[wv] = sq;
  __syncthreads();
  const float var = (r2[0]+r2[1]+r2[2]+r2[3]) * (1.0f/1024.0f);
  const float rs = rsqrtf(var + 1e-5f);
#pragma unroll
  for (int j = 0; j < 4; ++j){
    const int d = t + j*256;
    xn[(size_t)tok*1024 + d] = (__bf16)((u[j]-mean)*rs*lw[d] + lb[d]);
  }
}

// ------------------------------------------------- fused attention v2 (64 blocks, validated R6)
__global__ __launch_bounds__(256) void attn_fused(const __bf16* __restrict__ qkv,
                                                  __bf16* __restrict__ O){
  const int bh = blockIdx.x >> 1, half = blockIdx.x & 1;
  const int b = bh>>3, h = bh&7;
  const int tid = threadIdx.x, w = tid>>6, lane = tid&63;
  const int lr = lane&15, g = lane>>4;
  __shared__ __bf16 vt[128*128];    // V^T swizzled
  __shared__ __bf16 pl[4*2048];     // per-wave P (16x128), swizzled
  {
    const int n = tid >> 1, kh = tid & 1;
    const __bf16* vbase = qkv + (size_t)(b*128)*3072 + 2048 + h*128 + n;
#pragma unroll
    for (int jb = 0; jb < 8; ++jb){
      bf16x8_t pk;
#pragma unroll
      for (int e = 0; e < 8; ++e) pk[e] = vbase[(size_t)(kh*64 + jb*8 + e)*3072];
      const int cb = kh*8 + jb;
      *(bf16x8_t*)&vt[n*128 + ((cb ^ (n&7)) * 8)] = pk;
    }
  }
  const __bf16* qbase = qkv + (size_t)(b*128)*3072 + h*128;
  const __bf16* kbase = qbase + 1024;
  const int qrow0 = half*64 + w*16;
  f32x4_t acc[8] = {};
#pragma unroll
  for (int ks = 0; ks < 4; ++ks){
    bf16x8_t aq, bk[8];
    aq = *(const bf16x8_t*)(qbase + (size_t)(qrow0 + lr)*3072 + ks*32 + g*8);
#pragma unroll
    for (int j = 0; j < 8; ++j)
      bk[j] = *(const bf16x8_t*)(kbase + (size_t)(j*16 + lr)*3072 + ks*32 + g*8);
#pragma unroll
    for (int j = 0; j < 8; ++j)
      acc[j] = __builtin_amdgcn_mfma_f32_16x16x32_bf16(aq, bk[j], acc[j], 0, 0, 0);
  }
  __syncthreads();
  const float scale = 0.088388347648318447f;  // 1/sqrt(128)
#pragma unroll
  for (int r = 0; r < 4; ++r){
    const int row = g*4 + r;
    float sv[8];
    float mx = -1e30f;
#pragma unroll
    for (int j = 0; j < 8; ++j){ sv[j] = acc[j][r]*scale; mx = fmaxf(mx, sv[j]); }
#pragma unroll
    for (int o = 1; o < 16; o <<= 1) mx = fmaxf(mx, __shfl_xor(mx, o, 64));
    float s = 0;
#pragma unroll
    for (int j = 0; j < 8; ++j){ sv[j] = expf(sv[j]-mx); s += sv[j]; }
#pragma unroll
    for (int o = 1; o < 16; o <<= 1) s += __shfl_xor(s, o, 64);
    const float inv = 1.0f/s;
#pragma unroll
    for (int j = 0; j < 8; ++j){
      const int col = j*16 + lr;
      const int slot = (col>>3) ^ (row&7);
      pl[w*2048 + row*128 + slot*8 + (lr&7)] = (__bf16)(sv[j]*inv);
    }
  }
  __syncthreads();
  f32x4_t acc2[8] = {};
#pragma unroll
  for (int ks = 0; ks < 4; ++ks){
    bf16x8_t ap, bv[8];
    {
      const int row = lr;
      const int slot = (ks*4 + g) ^ (row&7);
      ap = *(bf16x8_t*)&pl[w*2048 + row*128 + slot*8];
    }
#pragma unroll
    for (int j = 0; j < 8; ++j){
      const int rowv = j*16 + lr;
      const int cb = ks*4 + g;
      bv[j] = *(bf16x8_t*)&vt[rowv*128 + ((cb ^ (rowv&7))*8)];
    }
#pragma unroll
    for (int j = 0; j < 8; ++j)
      acc2[j] = __builtin_amdgcn_mfma_f32_16x16x32_bf16(ap, bv[j], acc2[j], 0, 0, 0);
  }
#pragma unroll
  for (int j = 0; j < 8; ++j)
#pragma unroll
    for (int r = 0; r < 4; ++r){
      const int row = qrow0 + g*4 + r;
      const int col = j*16 + lr;
      O[(size_t)(b*128+row)*1024 + h*128 + col] = (__bf16)acc2[j][r];
    }
}

// ------------------------------------------------- head: c1 combine + BN + ReLU + c2 GEMV + centers
__global__ __launch_bounds__(256) void head_kernel(const float* __restrict__ parts,
                                                   const float* __restrict__ c1b,
                                                   const float* __restrict__ bnm,
                                                   const float* __restrict__ bnv,
                                                   const float* __restrict__ bng,
                                                   const float* __restrict__ bnb,
                                                   const float* __restrict__ c2w,
                                                   const float* __restrict__ c2b,
                                                   const float* __restrict__ centers,
                                                   float* __restrict__ out){
  const int tok = blockIdx.x, t = threadIdx.x;
  const int wv = t >> 6, lane = t & 63;
  __shared__ float hrow[1024];
#pragma unroll
  for (int j = 0; j < 4; ++j){
    const int d = t + j*256;
    const size_t idx = (size_t)tok*1024 + d;
    float s = 0;
#pragma unroll
    for (int z = 0; z < 8; ++z) s += parts[(size_t)z*524288 + idx];
    float v = s + c1b[d];
    v = (v - bnm[d]) * rsqrtf(bnv[d] + 1e-5f) * bng[d] + bnb[d];
    hrow[d] = fmaxf(v, 0.0f);
  }
  __syncthreads();
  for (int i = 0; i < 24; ++i){
    const int n = wv*24 + i;
    const float* wp = c2w + (size_t)n*1024;
    float s = 0;
#pragma unroll 4
    for (int j = 0; j < 16; ++j){
      const int k = lane + j*64;
      s += hrow[k] * wp[k];
    }
    s = wredsum(s);
    if (lane == 0) out[(size_t)tok*96 + n] = s + c2b[n] + centers[tok*3 + (n % 3)];
  }
}

// =================================================================
extern "C" void kernel_launch(void* const* d_in, const int* in_sizes, int n_in,
                              void* d_out, int out_size, void* d_ws, size_t ws_size,
                              hipStream_t stream){
  const float* lh   = (const float*)d_in[0];
  const float* pc   = (const float*)d_in[1];
  const float* fpw  = (const float*)d_in[2];
  const float* fpb  = (const float*)d_in[3];
  const float* spw  = (const float*)d_in[4];
  const float* spb  = (const float*)d_in[5];
  const float* pos  = (const float*)d_in[6];
  const float* ln1w = (const float*)d_in[7];
  const float* ln1b = (const float*)d_in[8];
  const float* inw  = (const float*)d_in[9];
  const float* inb  = (const float*)d_in[10];
  const float* outw = (const float*)d_in[11];
  const float* outb = (const float*)d_in[12];
  const float* ln2w = (const float*)d_in[13];
  const float* ln2b = (const float*)d_in[14];
  const float* w1   = (const float*)d_in[15];
  const float* b1   = (const float*)d_in[16];
  const float* w2   = (const float*)d_in[17];
  const float* b2   = (const float*)d_in[18];
  const float* c1w  = (const float*)d_in[19];
  const float* c1b  = (const float*)d_in[20];
  const float* bng  = (const float*)d_in[21];
  const float* bnbt = (const float*)d_in[22];
  const float* bnm  = (const float*)d_in[23];
  const float* bnv  = (const float*)d_in[24];
  const float* c2w  = (const float*)d_in[25];
  const float* c2b  = (const float*)d_in[26];
  float* out = (float*)d_out;

  // ---- workspace layout ----
  float* f = (float*)d_ws;
  float* parts = f;              f += 16*524288;  // split-K fp32 partials (32 MB)
  float* part  = f;              f += 131072;
  float* mlh   = f;              f += 16384;
  float* agg   = f;              f += 4096;
  float* x     = f;              f += 524288;     // residual stream fp32
  float* cent  = f;              f += 2048;       // centers (+pad)
  __bf16* bfp = (__bf16*)f;
  __bf16* xn   = bfp;            bfp += 524288;   // LN out bf16
  __bf16* qkv  = bfp;            bfp += 1572864;
  __bf16* obuf = bfp;            bfp += 524288;
  __bf16* hbf  = bfp;            bfp += 2097152;  // MLP hidden bf16
  __bf16* xbf  = bfp;            bfp += 524288;   // bf16 copy of final x
  __bf16* wbf  = bfp;            bfp += 51380224; // all weights bf16 (4 layers + c1 at +50331648)

  partial_kernel<<<dim3(16,8,4), 256, 0, stream>>>(lh, part);
  combine_kernel<<<64, 256, 0, stream>>>(part, mlh);
  agg_kernel<<<1024, 256, 0, stream>>>(mlh, fpw, fpb, agg);
  fused_front<<<7300, 1024, 0, stream>>>(pc, cent, agg, spw, spb, x,
                                         inw, outw, w1, w2, c1w, wbf);
  ln_kernel<<<512, 256, 0, stream>>>(x, pos, ln1w, ln1b, xn);

  for (int l = 0; l < 4; ++l){
    const __bf16* wl = wbf + (size_t)l*12582912;
    // qkv: 512x3072x1024, split-2 (192 blocks, nst=16)
    gemm_sk<<<dim3(24,4,2), 256, 0, stream>>>(xn, wl, parts, 512, 3072, 1024, 512);
    comb_qkv<<<6144, 256, 0, stream>>>(parts, inb + l*3072, qkv);
    attn_fused<<<64, 256, 0, stream>>>(qkv, obuf);
    // attn-out: 512x1024x1024, split-8 (256 blocks, nst=4)
    gemm_sk<<<dim3(8,4,8), 256, 0, stream>>>(obuf, wl + 3145728, parts, 512, 1024, 1024, 128);
    comb_res_ln<0><<<512, 256, 0, stream>>>(parts, 8, outb + l*1024, nullptr,
                                            ln2w + l*1024, ln2b + l*1024, x, xn);
    // mlp1: 512x4096x1024, split-2 (256 blocks, nst=16)
    gemm_sk<<<dim3(32,4,2), 256, 0, stream>>>(xn, wl + 4194304, parts, 512, 4096, 1024, 512);
    comb_gelu<<<8192, 256, 0, stream>>>(parts, b1 + l*4096, hbf);
    // mlp2: 512x1024x4096, split-8 (256 blocks, nst=16)
    gemm_sk<<<dim3(8,4,8), 256, 0, stream>>>(hbf, wl + 8388608, parts, 512, 1024, 4096, 512);
    if (l < 3)
      comb_res_ln<1><<<512, 256, 0, stream>>>(parts, 8, b2 + l*1024, pos,
                                              ln1w + (l+1)*1024, ln1b + (l+1)*1024, x, xn);
    else
      comb_res_ln<2><<<512, 256, 0, stream>>>(parts, 8, b2 + l*1024, nullptr,
                                              nullptr, nullptr, x, xbf);
  }

  // c1: 512x1024x1024, split-8 (256 blocks, nst=4); head fuses combine+BN+ReLU+c2+centers
  gemm_sk<<<dim3(8,4,8), 256, 0, stream>>>(xbf, wbf + 50331648, parts, 512, 1024, 1024, 128);
  head_kernel<<<512, 256, 0, stream>>>(parts, c1b, bnm, bnv, bng, bnbt, c2w, c2b, cent, out);
}

// Round 10
// 798.743 us; speedup vs baseline: 1.3394x; 1.0333x over previous
//
#include <hip/hip_runtime.h>
#include <hip/hip_bf16.h>
#include <math.h>

// Shapes (fixed): B=4, S=512, PH=4096, N=16384, D=1024, G=128, H=8, L=4, FF=4096, GS=32, HD=128

typedef __bf16 bf16x8_t __attribute__((ext_vector_type(8)));
typedef float  f32x4_t  __attribute__((ext_vector_type(4)));

__device__ __forceinline__ float wredsum(float v){
#pragma unroll
  for (int o = 32; o; o >>= 1) v += __shfl_down(v, o, 64);
  return v;  // valid in lane 0
}

__device__ __forceinline__ bf16x8_t pack8(float4 a, float4 b){
  bf16x8_t v;
  v[0]=(__bf16)a.x; v[1]=(__bf16)a.y; v[2]=(__bf16)a.z; v[3]=(__bf16)a.w;
  v[4]=(__bf16)b.x; v[5]=(__bf16)b.y; v[6]=(__bf16)b.z; v[7]=(__bf16)b.w;
  return v;
}

__device__ __forceinline__ void gload16(const void* g, void* l){
  __builtin_amdgcn_global_load_lds((const __attribute__((address_space(1))) unsigned int*)g,
                                   (__attribute__((address_space(3))) unsigned int*)l, 16, 0, 0);
}

// ---------------------------------------------------------------- fused front-end
// blocks 0..3: FPS; 4..1027: sp GEMV (537 MB); 1028..7299: weight fp32->bf16 (308 MB)
__global__ __launch_bounds__(1024) void fused_front(
  const float* __restrict__ pc, float* __restrict__ centers,
  const float* __restrict__ agg, const float* __restrict__ spw,
  const float* __restrict__ spb, float* __restrict__ x,
  const float* __restrict__ inw, const float* __restrict__ outw,
  const float* __restrict__ w1, const float* __restrict__ w2,
  const float* __restrict__ c1w, __bf16* __restrict__ wbf)
{
  const int bid = blockIdx.x;
  const int tid = threadIdx.x;
  if (bid < 4){
    // ---------------- FPS v3 (validated) ----------------
    const int b = bid;
    const int lane = tid & 63;
    const float* base = pc + (size_t)b * 16384 * 3;
    float px[16], py[16], pz[16], dist[16];
    {
      union { float4 v4[12]; float f[48]; } u;
      const float4* src = (const float4*)(base + tid * 48);
#pragma unroll
      for (int q = 0; q < 12; ++q) u.v4[q] = src[q];
#pragma unroll
      for (int j = 0; j < 16; ++j){
        px[j] = u.f[j*3]; py[j] = u.f[j*3+1]; pz[j] = u.f[j*3+2];
        dist[j] = 1e10f;
      }
    }
    __shared__ unsigned long long keyslot[128];
    for (int i = tid; i < 128; i += 1024) keyslot[i] = 0ULL;
    __syncthreads();
    float cx = base[0], cy = base[1], cz = base[2];
    for (int t = 0; t < 128; ++t){
      if (tid == 0){
        centers[(b*128+t)*3+0] = cx;
        centers[(b*128+t)*3+1] = cy;
        centers[(b*128+t)*3+2] = cz;
      }
      if (t == 127) break;
      float bmax = -1.0f; int bidx = 0;
#pragma unroll
      for (int j = 0; j < 16; ++j){
        float dx = __fsub_rn(px[j], cx);
        float dy = __fsub_rn(py[j], cy);
        float dz = __fsub_rn(pz[j], cz);
        float d  = __fadd_rn(__fadd_rn(__fmul_rn(dx,dx), __fmul_rn(dy,dy)), __fmul_rn(dz,dz));
        float nd = fminf(dist[j], d);
        dist[j] = nd;
        if (nd > bmax){ bmax = nd; bidx = tid*16 + j; }
      }
      unsigned long long key = ((unsigned long long)__float_as_uint(bmax) << 32)
                             | (unsigned long long)(0xFFFFFFFFu - (unsigned)bidx);
#pragma unroll
      for (int o = 32; o; o >>= 1){
        unsigned long long ok = __shfl_down(key, o, 64);
        if (ok > key) key = ok;
      }
      if (lane == 0) atomicMax(&keyslot[t], key);
      __syncthreads();
      const unsigned long long gk = keyslot[t];
      const unsigned gidx = 0xFFFFFFFFu - (unsigned)(gk & 0xFFFFFFFFu);
      const float* cp = base + (size_t)gidx*3;
      cx = cp[0]; cy = cp[1]; cz = cp[2];
    }
  } else if (bid < 1028){
    // ---------------- sp: x0 = agg @ sp_w.T + sp_b ----------------
    __shared__ float ag[4096];
    for (int i = tid; i < 4096; i += 1024) ag[i] = agg[i];
    __syncthreads();
    const int wv = tid >> 6, lane = tid & 63;
    const int rbase = ((bid - 4)*16 + wv)*8;
    for (int rr = 0; rr < 8; ++rr){
      const int row = rbase + rr;
      const float* wp = spw + (size_t)row*1024 + lane*4;
      const float4 w0 = *(const float4*)(wp      );
      const float4 wq1 = *(const float4*)(wp + 256);
      const float4 wq2 = *(const float4*)(wp + 512);
      const float4 wq3 = *(const float4*)(wp + 768);
      float acc[4];
#pragma unroll
      for (int bb = 0; bb < 4; ++bb){
        const float* gp = &ag[bb*1024 + lane*4];
        const float4 g0 = *(const float4*)(gp      );
        const float4 g1 = *(const float4*)(gp + 256);
        const float4 g2 = *(const float4*)(gp + 512);
        const float4 g3 = *(const float4*)(gp + 768);
        acc[bb] = w0.x*g0.x + w0.y*g0.y + w0.z*g0.z + w0.w*g0.w
                + wq1.x*g1.x + wq1.y*g1.y + wq1.z*g1.z + wq1.w*g1.w
                + wq2.x*g2.x + wq2.y*g2.y + wq2.z*g2.z + wq2.w*g2.w
                + wq3.x*g3.x + wq3.y*g3.y + wq3.z*g3.z + wq3.w*g3.w;
      }
      float a0 = wredsum(acc[0]);
      float a1 = wredsum(acc[1]);
      float a2 = wredsum(acc[2]);
      float a3 = wredsum(acc[3]);
      if (lane == 0){
        const float bias = spb[row];
        x[(size_t)0*131072 + row] = a0 + bias;
        x[(size_t)1*131072 + row] = a1 + bias;
        x[(size_t)2*131072 + row] = a2 + bias;
        x[(size_t)3*131072 + row] = a3 + bias;
      }
    }
  } else {
    // ---------------- weight fp32 -> bf16 (all 4 layers + c1) ----------------
    const size_t t = (size_t)(bid - 1028)*1024 + tid;   // exactly 6272*1024 chunks
    const size_t i = t*8;
    const float* src;
    if (i < 50331648){
      const size_t l = i / 12582912, r = i - l*12582912;
      if (r < 3145728)       src = inw  + l*3145728 + r;
      else if (r < 4194304)  src = outw + l*1048576 + (r-3145728);
      else if (r < 8388608)  src = w1   + l*4194304 + (r-4194304);
      else                   src = w2   + l*4194304 + (r-8388608);
    } else src = c1w + (i - 50331648);
    float4 a = *(const float4*)src, bq = *(const float4*)(src+4);
    *(bf16x8_t*)(wbf + i) = pack8(a, bq);
  }
}

// ------------------------------------------------- mean over S (2-stage)
__global__ __launch_bounds__(256) void partial_kernel(const float* __restrict__ lh,
                                                      float* __restrict__ part){
  const int ph = blockIdx.x*256 + threadIdx.x;
  const int sc = blockIdx.y, b = blockIdx.z;
  const float* p = lh + ((size_t)b*512 + sc*64)*4096 + ph;
  float s0=0,s1=0,s2=0,s3=0;
  for (int j = 0; j < 64; j += 4){
    s0 += p[(size_t)(j+0)*4096];
    s1 += p[(size_t)(j+1)*4096];
    s2 += p[(size_t)(j+2)*4096];
    s3 += p[(size_t)(j+3)*4096];
  }
  part[(size_t)(b*8+sc)*4096 + ph] = (s0+s1)+(s2+s3);
}

__global__ __launch_bounds__(256) void combine_kernel(const float* __restrict__ part,
                                                      float* __restrict__ mlh){
  const int i = blockIdx.x*256 + threadIdx.x;
  const int b = i >> 12, ph = i & 4095;
  float s = 0;
#pragma unroll
  for (int sc = 0; sc < 8; ++sc) s += part[(size_t)(b*8+sc)*4096 + ph];
  mlh[i] = s * (1.0f/512.0f);
}

// ------------------------------------------------- agg = mean_lh @ fp_w.T + fp_b
__global__ __launch_bounds__(256) void agg_kernel(const float* __restrict__ mlh,
                                                  const float* __restrict__ fpw,
                                                  const float* __restrict__ fpb,
                                                  float* __restrict__ agg){
  const int o = blockIdx.x*4 + (threadIdx.x>>6);
  const int lane = threadIdx.x & 63;
  const int b = o >> 10, d = o & 1023;
  const float* mp = mlh + b*4096;
  const float* wp = fpw + (size_t)d*4096;
  float s = 0;
#pragma unroll 4
  for (int j = 0; j < 64; ++j){
    int ph = lane + j*64;
    s += mp[ph] * wp[ph];
  }
  s = wredsum(s);
  if (lane == 0) agg[o] = s + fpb[d];
}

// ------------------------------------------------- LayerNorm (optional +pos), bf16 out
__global__ __launch_bounds__(256) void ln_kernel(const float* __restrict__ x,
                                                 const float* __restrict__ pos,
                                                 const float* __restrict__ w,
                                                 const float* __restrict__ bb,
                                                 __bf16* __restrict__ out){
  const int tok = blockIdx.x, g = tok & 127, t = threadIdx.x;
  const int lane = t & 63, wv = t >> 6;
  const float* xr = x + (size_t)tok*1024;
  float v[4];
#pragma unroll
  for (int j = 0; j < 4; ++j){
    int d = t + j*256;
    float val = xr[d];
    if (pos) val += pos[g*1024 + d];
    v[j] = val;
  }
  __shared__ float r1[4], r2[4];
  float s = wredsum(v[0]+v[1]+v[2]+v[3]);
  if (lane == 0) r1[wv] = s;
  __syncthreads();
  const float mean = (r1[0]+r1[1]+r1[2]+r1[3]) * (1.0f/1024.0f);
  float sq = 0;
#pragma unroll
  for (int j = 0; j < 4; ++j){ float d0 = v[j]-mean; sq += d0*d0; }
  sq = wredsum(sq);
  if (lane == 0) r2[wv] = sq;
  __syncthreads();
  const float var = (r2[0]+r2[1]+r2[2]+r2[3]) * (1.0f/1024.0f);
  const float rs = rsqrtf(var + 1e-5f);
#pragma unroll
  for (int j = 0; j < 4; ++j){
    int d = t + j*256;
    out[(size_t)tok*1024 + d] = (__bf16)((v[j]-mean)*rs*w[d] + bb[d]);
  }
}

// ------------------------------------------------- bf16 MFMA split-K GEMM, 128x128 tile, BK=64
// Single-buffer 2-barrier loop (validated structure), BK=64 so each staging covers TWO
// K=32 MFMA sub-iterations (halves the exposed vmcnt-drain count vs BK=32).
// LDS rows are 128B -> XOR quarter-swizzle (T2): stored(row, q') = global(row, q'^(row&7)).
// global_load_lds dest stays LINEAR (c*16 = wave base + lane*16, rule #21); the per-lane
// GLOBAL source is pre-swizzled; reads use q' = lq ^ (row&7). Bank spread: 2/bank (free).
// kc must be a multiple of 64.
__global__ __launch_bounds__(256) void gemm_sk(
  const __bf16* __restrict__ A, const __bf16* __restrict__ W,
  float* __restrict__ parts, int M, int N, int K, int kc)
{
  __shared__ __bf16 As[128*64];
  __shared__ __bf16 Ws[128*64];
  const int n0 = blockIdx.x*128, m0 = blockIdx.y*128, z = blockIdx.z;
  const int tid = threadIdx.x;
  const int lane = tid & 63, w = tid >> 6;
  const int wm = w >> 1, wn = w & 1;
  const int lr = lane & 15, g = lane >> 4;
  const int kbeg = z*kc, kend = kbeg + kc;
  // staging chunks: c = tid + i*256 (i<4); row = c>>3, physical quarter q' = c&7;
  // global source quarter = q' ^ (row&7)
  const int c0 = tid, c1 = tid+256, c2 = tid+512, c3 = tid+768;
  const int r0 = c0>>3, r1 = c1>>3, r2 = c2>>3, r3 = c3>>3;
  const int s0 = ((c0&7) ^ (r0&7))*8, s1 = ((c1&7) ^ (r1&7))*8;
  const int s2 = ((c2&7) ^ (r2&7))*8, s3 = ((c3&7) ^ (r3&7))*8;
  const __bf16* pa0 = A + (size_t)(m0+r0)*K + kbeg + s0;
  const __bf16* pa1 = A + (size_t)(m0+r1)*K + kbeg + s1;
  const __bf16* pa2 = A + (size_t)(m0+r2)*K + kbeg + s2;
  const __bf16* pa3 = A + (size_t)(m0+r3)*K + kbeg + s3;
  const __bf16* pw0 = W + (size_t)(n0+r0)*K + kbeg + s0;
  const __bf16* pw1 = W + (size_t)(n0+r1)*K + kbeg + s1;
  const __bf16* pw2 = W + (size_t)(n0+r2)*K + kbeg + s2;
  const __bf16* pw3 = W + (size_t)(n0+r3)*K + kbeg + s3;
  f32x4_t acc[4][4] = {};
  for (int k0 = 0; k0 < kc; k0 += 64){
    __syncthreads();
    gload16(pa0 + k0, &As[c0*8]);
    gload16(pa1 + k0, &As[c1*8]);
    gload16(pa2 + k0, &As[c2*8]);
    gload16(pa3 + k0, &As[c3*8]);
    gload16(pw0 + k0, &Ws[c0*8]);
    gload16(pw1 + k0, &Ws[c1*8]);
    gload16(pw2 + k0, &Ws[c2*8]);
    gload16(pw3 + k0, &Ws[c3*8]);
    __syncthreads();
#pragma unroll
    for (int ks2 = 0; ks2 < 2; ++ks2){
      bf16x8_t af[4], bf[4];
#pragma unroll
      for (int f = 0; f < 4; ++f){
        const int ra = wm*64 + f*16 + lr;
        const int rb = wn*64 + f*16 + lr;
        const int lq = ks2*4 + g;
        af[f] = *(bf16x8_t*)&As[ra*64 + (lq ^ (ra&7))*8];
        bf[f] = *(bf16x8_t*)&Ws[rb*64 + (lq ^ (rb&7))*8];
      }
#pragma unroll
      for (int i = 0; i < 4; ++i)
#pragma unroll
        for (int j = 0; j < 4; ++j)
          acc[i][j] = __builtin_amdgcn_mfma_f32_16x16x32_bf16(af[i], bf[j], acc[i][j], 0, 0, 0);
    }
  }
  float* C = parts + (size_t)z*M*N;
#pragma unroll
  for (int i = 0; i < 4; ++i)
#pragma unroll
    for (int j = 0; j < 4; ++j)
#pragma unroll
      for (int r = 0; r < 4; ++r){
        const int row = m0 + wm*64 + i*16 + g*4 + r;
        const int col = n0 + wn*64 + j*16 + lr;
        C[(size_t)row*N + col] = acc[i][j][r];
      }
}

// ------------------------------------------------- combines (2-split versions, validated)
__global__ __launch_bounds__(256) void comb_qkv(const float* __restrict__ parts,
                                                const float* __restrict__ bias,
                                                __bf16* __restrict__ out){
  const int i = blockIdx.x*256 + threadIdx.x;   // < 1572864
  const int col = i % 3072;
  out[i] = (__bf16)(parts[i] + parts[1572864 + i] + bias[col]);
}

__global__ __launch_bounds__(256) void comb_gelu(const float* __restrict__ parts,
                                                 const float* __restrict__ bias,
                                                 __bf16* __restrict__ out){
  const int i = blockIdx.x*256 + threadIdx.x;   // < 2097152
  const int col = i & 4095;
  float v = parts[i] + parts[2097152 + i] + bias[col];
  v = v * 0.5f * (1.0f + erff(v * 0.70710678118654752440f));
  out[i] = (__bf16)v;
}

// residual add (+bias, nsplit fp32 partials) into x, then optional LayerNorm -> bf16 xn.
// MODE 0: LN; MODE 1: LN with pos added to LN input; MODE 2: no LN, emit bf16 copy of x.
template<int MODE>
__global__ __launch_bounds__(256) void comb_res_ln(const float* __restrict__ parts, int nsplit,
                                                   const float* __restrict__ bias,
                                                   const float* __restrict__ pos,
                                                   const float* __restrict__ lw,
                                                   const float* __restrict__ lb,
                                                   float* __restrict__ x,
                                                   __bf16* __restrict__ xn){
  const int tok = blockIdx.x, gi = tok & 127, t = threadIdx.x;
  const int lane = t & 63, wv = t >> 6;
  float v[4];
#pragma unroll
  for (int j = 0; j < 4; ++j){
    const int d = t + j*256;
    const size_t idx = (size_t)tok*1024 + d;
    float s = 0;
    for (int z = 0; z < nsplit; ++z) s += parts[(size_t)z*524288 + idx];
    float val = x[idx] + s + bias[d];
    x[idx] = val;
    v[j] = val;
  }
  if (MODE == 2){
#pragma unroll
    for (int j = 0; j < 4; ++j){
      const int d = t + j*256;
      xn[(size_t)tok*1024 + d] = (__bf16)v[j];
    }
    return;
  }
  float u[4];
#pragma unroll
  for (int j = 0; j < 4; ++j){
    const int d = t + j*256;
    u[j] = v[j] + (MODE == 1 ? pos[gi*1024 + d] : 0.0f);
  }
  __shared__ float r1[4], r2[4];
  float s1 = wredsum(u[0]+u[1]+u[2]+u[3]);
  if (lane == 0) r1[wv] = s1;
  __syncthreads();
  const float mean = (r1[0]+r1[1]+r1[2]+r1[3]) * (1.0f/1024.0f);
  float sq = 0;
#pragma unroll
  for (int j = 0; j < 4; ++j){ float d0 = u[j]-mean; sq += d0*d0; }
  sq = wredsum(sq);
  if (lane == 0) r2[wv] = sq;
  __syncthreads();
  const float var = (r2[0]+r2[1]+r2[2]+r2[3]) * (1.0f/1024.0f);
  const float rs = rsqrtf(var + 1e-5f);
#pragma unroll
  for (int j = 0; j < 4; ++j){
    const int d = t + j*256;
    xn[(size_t)tok*1024 + d] = (__bf16)((u[j]-mean)*rs*lw[d] + lb[d]);
  }
}

// ------------------------------------------------- fused attention v2 (64 blocks, validated R6)
__global__ __launch_bounds__(256) void attn_fused(const __bf16* __restrict__ qkv,
                                                  __bf16* __restrict__ O){
  const int bh = blockIdx.x >> 1, half = blockIdx.x & 1;
  const int b = bh>>3, h = bh&7;
  const int tid = threadIdx.x, w = tid>>6, lane = tid&63;
  const int lr = lane&15, g = lane>>4;
  __shared__ __bf16 vt[128*128];    // V^T swizzled
  __shared__ __bf16 pl[4*2048];     // per-wave P (16x128), swizzled
  {
    const int n = tid >> 1, kh = tid & 1;
    const __bf16* vbase = qkv + (size_t)(b*128)*3072 + 2048 + h*128 + n;
#pragma unroll
    for (int jb = 0; jb < 8; ++jb){
      bf16x8_t pk;
#pragma unroll
      for (int e = 0; e < 8; ++e) pk[e] = vbase[(size_t)(kh*64 + jb*8 + e)*3072];
      const int cb = kh*8 + jb;
      *(bf16x8_t*)&vt[n*128 + ((cb ^ (n&7)) * 8)] = pk;
    }
  }
  const __bf16* qbase = qkv + (size_t)(b*128)*3072 + h*128;
  const __bf16* kbase = qbase + 1024;
  const int qrow0 = half*64 + w*16;
  f32x4_t acc[8] = {};
#pragma unroll
  for (int ks = 0; ks < 4; ++ks){
    bf16x8_t aq, bk[8];
    aq = *(const bf16x8_t*)(qbase + (size_t)(qrow0 + lr)*3072 + ks*32 + g*8);
#pragma unroll
    for (int j = 0; j < 8; ++j)
      bk[j] = *(const bf16x8_t*)(kbase + (size_t)(j*16 + lr)*3072 + ks*32 + g*8);
#pragma unroll
    for (int j = 0; j < 8; ++j)
      acc[j] = __builtin_amdgcn_mfma_f32_16x16x32_bf16(aq, bk[j], acc[j], 0, 0, 0);
  }
  __syncthreads();
  const float scale = 0.088388347648318447f;  // 1/sqrt(128)
#pragma unroll
  for (int r = 0; r < 4; ++r){
    const int row = g*4 + r;
    float sv[8];
    float mx = -1e30f;
#pragma unroll
    for (int j = 0; j < 8; ++j){ sv[j] = acc[j][r]*scale; mx = fmaxf(mx, sv[j]); }
#pragma unroll
    for (int o = 1; o < 16; o <<= 1) mx = fmaxf(mx, __shfl_xor(mx, o, 64));
    float s = 0;
#pragma unroll
    for (int j = 0; j < 8; ++j){ sv[j] = expf(sv[j]-mx); s += sv[j]; }
#pragma unroll
    for (int o = 1; o < 16; o <<= 1) s += __shfl_xor(s, o, 64);
    const float inv = 1.0f/s;
#pragma unroll
    for (int j = 0; j < 8; ++j){
      const int col = j*16 + lr;
      const int slot = (col>>3) ^ (row&7);
      pl[w*2048 + row*128 + slot*8 + (lr&7)] = (__bf16)(sv[j]*inv);
    }
  }
  __syncthreads();
  f32x4_t acc2[8] = {};
#pragma unroll
  for (int ks = 0; ks < 4; ++ks){
    bf16x8_t ap, bv[8];
    {
      const int row = lr;
      const int slot = (ks*4 + g) ^ (row&7);
      ap = *(bf16x8_t*)&pl[w*2048 + row*128 + slot*8];
    }
#pragma unroll
    for (int j = 0; j < 8; ++j){
      const int rowv = j*16 + lr;
      const int cb = ks*4 + g;
      bv[j] = *(bf16x8_t*)&vt[rowv*128 + ((cb ^ (rowv&7))*8)];
    }
#pragma unroll
    for (int j = 0; j < 8; ++j)
      acc2[j] = __builtin_amdgcn_mfma_f32_16x16x32_bf16(ap, bv[j], acc2[j], 0, 0, 0);
  }
#pragma unroll
  for (int j = 0; j < 8; ++j)
#pragma unroll
    for (int r = 0; r < 4; ++r){
      const int row = qrow0 + g*4 + r;
      const int col = j*16 + lr;
      O[(size_t)(b*128+row)*1024 + h*128 + col] = (__bf16)acc2[j][r];
    }
}

// ------------------------------------------------- head: c1 combine + BN + ReLU + c2 GEMV + centers
__global__ __launch_bounds__(256) void head_kernel(const float* __restrict__ parts,
                                                   const float* __restrict__ c1b,
                                                   const float* __restrict__ bnm,
                                                   const float* __restrict__ bnv,
                                                   const float* __restrict__ bng,
                                                   const float* __restrict__ bnb,
                                                   const float* __restrict__ c2w,
                                                   const float* __restrict__ c2b,
                                                   const float* __restrict__ centers,
                                                   float* __restrict__ out){
  const int tok = blockIdx.x, t = threadIdx.x;
  const int wv = t >> 6, lane = t & 63;
  __shared__ float hrow[1024];
#pragma unroll
  for (int j = 0; j < 4; ++j){
    const int d = t + j*256;
    const size_t idx = (size_t)tok*1024 + d;
    float s = 0;
#pragma unroll
    for (int z = 0; z < 8; ++z) s += parts[(size_t)z*524288 + idx];
    float v = s + c1b[d];
    v = (v - bnm[d]) * rsqrtf(bnv[d] + 1e-5f) * bng[d] + bnb[d];
    hrow[d] = fmaxf(v, 0.0f);
  }
  __syncthreads();
  for (int i = 0; i < 24; ++i){
    const int n = wv*24 + i;
    const float* wp = c2w + (size_t)n*1024;
    float s = 0;
#pragma unroll 4
    for (int j = 0; j < 16; ++j){
      const int k = lane + j*64;
      s += hrow[k] * wp[k];
    }
    s = wredsum(s);
    if (lane == 0) out[(size_t)tok*96 + n] = s + c2b[n] + centers[tok*3 + (n % 3)];
  }
}

// =================================================================
extern "C" void kernel_launch(void* const* d_in, const int* in_sizes, int n_in,
                              void* d_out, int out_size, void* d_ws, size_t ws_size,
                              hipStream_t stream){
  const float* lh   = (const float*)d_in[0];
  const float* pc   = (const float*)d_in[1];
  const float* fpw  = (const float*)d_in[2];
  const float* fpb  = (const float*)d_in[3];
  const float* spw  = (const float*)d_in[4];
  const float* spb  = (const float*)d_in[5];
  const float* pos  = (const float*)d_in[6];
  const float* ln1w = (const float*)d_in[7];
  const float* ln1b = (const float*)d_in[8];
  const float* inw  = (const float*)d_in[9];
  const float* inb  = (const float*)d_in[10];
  const float* outw = (const float*)d_in[11];
  const float* outb = (const float*)d_in[12];
  const float* ln2w = (const float*)d_in[13];
  const float* ln2b = (const float*)d_in[14];
  const float* w1   = (const float*)d_in[15];
  const float* b1   = (const float*)d_in[16];
  const float* w2   = (const float*)d_in[17];
  const float* b2   = (const float*)d_in[18];
  const float* c1w  = (const float*)d_in[19];
  const float* c1b  = (const float*)d_in[20];
  const float* bng  = (const float*)d_in[21];
  const float* bnbt = (const float*)d_in[22];
  const float* bnm  = (const float*)d_in[23];
  const float* bnv  = (const float*)d_in[24];
  const float* c2w  = (const float*)d_in[25];
  const float* c2b  = (const float*)d_in[26];
  float* out = (float*)d_out;

  // ---- workspace layout ----
  float* f = (float*)d_ws;
  float* parts = f;              f += 16*524288;  // split-K fp32 partials (32 MB)
  float* part  = f;              f += 131072;
  float* mlh   = f;              f += 16384;
  float* agg   = f;              f += 4096;
  float* x     = f;              f += 524288;     // residual stream fp32
  float* cent  = f;              f += 2048;       // centers (+pad)
  __bf16* bfp = (__bf16*)f;
  __bf16* xn   = bfp;            bfp += 524288;   // LN out bf16
  __bf16* qkv  = bfp;            bfp += 1572864;
  __bf16* obuf = bfp;            bfp += 524288;
  __bf16* hbf  = bfp;            bfp += 2097152;  // MLP hidden bf16
  __bf16* xbf  = bfp;            bfp += 524288;   // bf16 copy of final x
  __bf16* wbf  = bfp;            bfp += 51380224; // all weights bf16 (4 layers + c1 at +50331648)

  partial_kernel<<<dim3(16,8,4), 256, 0, stream>>>(lh, part);
  combine_kernel<<<64, 256, 0, stream>>>(part, mlh);
  agg_kernel<<<1024, 256, 0, stream>>>(mlh, fpw, fpb, agg);
  fused_front<<<7300, 1024, 0, stream>>>(pc, cent, agg, spw, spb, x,
                                         inw, outw, w1, w2, c1w, wbf);
  ln_kernel<<<512, 256, 0, stream>>>(x, pos, ln1w, ln1b, xn);

  for (int l = 0; l < 4; ++l){
    const __bf16* wl = wbf + (size_t)l*12582912;
    // qkv: 512x3072x1024, split-2 (192 blocks, 8 BK64-steps)
    gemm_sk<<<dim3(24,4,2), 256, 0, stream>>>(xn, wl, parts, 512, 3072, 1024, 512);
    comb_qkv<<<6144, 256, 0, stream>>>(parts, inb + l*3072, qkv);
    attn_fused<<<64, 256, 0, stream>>>(qkv, obuf);
    // attn-out: 512x1024x1024, split-8 (256 blocks, 2 steps)
    gemm_sk<<<dim3(8,4,8), 256, 0, stream>>>(obuf, wl + 3145728, parts, 512, 1024, 1024, 128);
    comb_res_ln<0><<<512, 256, 0, stream>>>(parts, 8, outb + l*1024, nullptr,
                                            ln2w + l*1024, ln2b + l*1024, x, xn);
    // mlp1: 512x4096x1024, split-2 (256 blocks, 8 steps)
    gemm_sk<<<dim3(32,4,2), 256, 0, stream>>>(xn, wl + 4194304, parts, 512, 4096, 1024, 512);
    comb_gelu<<<8192, 256, 0, stream>>>(parts, b1 + l*4096, hbf);
    // mlp2: 512x1024x4096, split-8 (256 blocks, 8 steps)
    gemm_sk<<<dim3(8,4,8), 256, 0, stream>>>(hbf, wl + 8388608, parts, 512, 1024, 4096, 512);
    if (l < 3)
      comb_res_ln<1><<<512, 256, 0, stream>>>(parts, 8, b2 + l*1024, pos,
                                              ln1w + (l+1)*1024, ln1b + (l+1)*1024, x, xn);
    else
      comb_res_ln<2><<<512, 256, 0, stream>>>(parts, 8, b2 + l*1024, nullptr,
                                              nullptr, nullptr, x, xbf);
  }

  // c1: 512x1024x1024, split-8 (256 blocks, 2 steps); head fuses combine+BN+ReLU+c2+centers
  gemm_sk<<<dim3(8,4,8), 256, 0, stream>>>(xbf, wbf + 50331648, parts, 512, 1024, 1024, 128);
  head_kernel<<<512, 256, 0, stream>>>(parts, c1b, bnm, bnv, bng, bnbt, c2w, c2b, cent, out);
}

// Round 11
// 794.051 us; speedup vs baseline: 1.3473x; 1.0059x over previous
//
#include <hip/hip_runtime.h>
#include <hip/hip_bf16.h>
#include <math.h>

// Shapes (fixed): B=4, S=512, PH=4096, N=16384, D=1024, G=128, H=8, L=4, FF=4096, GS=32, HD=128

typedef __bf16 bf16x8_t __attribute__((ext_vector_type(8)));
typedef float  f32x4_t  __attribute__((ext_vector_type(4)));

__device__ __forceinline__ float wredsum(float v){
#pragma unroll
  for (int o = 32; o; o >>= 1) v += __shfl_down(v, o, 64);
  return v;  // valid in lane 0
}

__device__ __forceinline__ bf16x8_t pack8(float4 a, float4 b){
  bf16x8_t v;
  v[0]=(__bf16)a.x; v[1]=(__bf16)a.y; v[2]=(__bf16)a.z; v[3]=(__bf16)a.w;
  v[4]=(__bf16)b.x; v[5]=(__bf16)b.y; v[6]=(__bf16)b.z; v[7]=(__bf16)b.w;
  return v;
}

__device__ __forceinline__ void gload16(const void* g, void* l){
  __builtin_amdgcn_global_load_lds((const __attribute__((address_space(1))) unsigned int*)g,
                                   (__attribute__((address_space(3))) unsigned int*)l, 16, 0, 0);
}

// ---------------------------------------------------------------- fused front-end
// blocks 0..3: FPS; 4..1027: sp GEMV (537 MB); 1028..2563: LAYER-0 weight fp32->bf16 only
// (layers 1-3 + c1 conversions are hidden under each layer's attn dispatch).
__global__ __launch_bounds__(1024) void fused_front(
  const float* __restrict__ pc, float* __restrict__ centers,
  const float* __restrict__ agg, const float* __restrict__ spw,
  const float* __restrict__ spb, float* __restrict__ x,
  const float* __restrict__ inw, const float* __restrict__ outw,
  const float* __restrict__ w1, const float* __restrict__ w2,
  __bf16* __restrict__ wbf)
{
  const int bid = blockIdx.x;
  const int tid = threadIdx.x;
  if (bid < 4){
    // ---------------- FPS v3 (validated) ----------------
    const int b = bid;
    const int lane = tid & 63;
    const float* base = pc + (size_t)b * 16384 * 3;
    float px[16], py[16], pz[16], dist[16];
    {
      union { float4 v4[12]; float f[48]; } u;
      const float4* src = (const float4*)(base + tid * 48);
#pragma unroll
      for (int q = 0; q < 12; ++q) u.v4[q] = src[q];
#pragma unroll
      for (int j = 0; j < 16; ++j){
        px[j] = u.f[j*3]; py[j] = u.f[j*3+1]; pz[j] = u.f[j*3+2];
        dist[j] = 1e10f;
      }
    }
    __shared__ unsigned long long keyslot[128];
    for (int i = tid; i < 128; i += 1024) keyslot[i] = 0ULL;
    __syncthreads();
    float cx = base[0], cy = base[1], cz = base[2];
    for (int t = 0; t < 128; ++t){
      if (tid == 0){
        centers[(b*128+t)*3+0] = cx;
        centers[(b*128+t)*3+1] = cy;
        centers[(b*128+t)*3+2] = cz;
      }
      if (t == 127) break;
      float bmax = -1.0f; int bidx = 0;
#pragma unroll
      for (int j = 0; j < 16; ++j){
        float dx = __fsub_rn(px[j], cx);
        float dy = __fsub_rn(py[j], cy);
        float dz = __fsub_rn(pz[j], cz);
        float d  = __fadd_rn(__fadd_rn(__fmul_rn(dx,dx), __fmul_rn(dy,dy)), __fmul_rn(dz,dz));
        float nd = fminf(dist[j], d);
        dist[j] = nd;
        if (nd > bmax){ bmax = nd; bidx = tid*16 + j; }
      }
      unsigned long long key = ((unsigned long long)__float_as_uint(bmax) << 32)
                             | (unsigned long long)(0xFFFFFFFFu - (unsigned)bidx);
#pragma unroll
      for (int o = 32; o; o >>= 1){
        unsigned long long ok = __shfl_down(key, o, 64);
        if (ok > key) key = ok;
      }
      if (lane == 0) atomicMax(&keyslot[t], key);
      __syncthreads();
      const unsigned long long gk = keyslot[t];
      const unsigned gidx = 0xFFFFFFFFu - (unsigned)(gk & 0xFFFFFFFFu);
      const float* cp = base + (size_t)gidx*3;
      cx = cp[0]; cy = cp[1]; cz = cp[2];
    }
  } else if (bid < 1028){
    // ---------------- sp: x0 = agg @ sp_w.T + sp_b ----------------
    __shared__ float ag[4096];
    for (int i = tid; i < 4096; i += 1024) ag[i] = agg[i];
    __syncthreads();
    const int wv = tid >> 6, lane = tid & 63;
    const int rbase = ((bid - 4)*16 + wv)*8;
    for (int rr = 0; rr < 8; ++rr){
      const int row = rbase + rr;
      const float* wp = spw + (size_t)row*1024 + lane*4;
      const float4 w0 = *(const float4*)(wp      );
      const float4 wq1 = *(const float4*)(wp + 256);
      const float4 wq2 = *(const float4*)(wp + 512);
      const float4 wq3 = *(const float4*)(wp + 768);
      float acc[4];
#pragma unroll
      for (int bb = 0; bb < 4; ++bb){
        const float* gp = &ag[bb*1024 + lane*4];
        const float4 g0 = *(const float4*)(gp      );
        const float4 g1 = *(const float4*)(gp + 256);
        const float4 g2 = *(const float4*)(gp + 512);
        const float4 g3 = *(const float4*)(gp + 768);
        acc[bb] = w0.x*g0.x + w0.y*g0.y + w0.z*g0.z + w0.w*g0.w
                + wq1.x*g1.x + wq1.y*g1.y + wq1.z*g1.z + wq1.w*g1.w
                + wq2.x*g2.x + wq2.y*g2.y + wq2.z*g2.z + wq2.w*g2.w
                + wq3.x*g3.x + wq3.y*g3.y + wq3.z*g3.z + wq3.w*g3.w;
      }
      float a0 = wredsum(acc[0]);
      float a1 = wredsum(acc[1]);
      float a2 = wredsum(acc[2]);
      float a3 = wredsum(acc[3]);
      if (lane == 0){
        const float bias = spb[row];
        x[(size_t)0*131072 + row] = a0 + bias;
        x[(size_t)1*131072 + row] = a1 + bias;
        x[(size_t)2*131072 + row] = a2 + bias;
        x[(size_t)3*131072 + row] = a3 + bias;
      }
    }
  } else {
    // ---------------- weight fp32 -> bf16, LAYER 0 only (1536 blocks x 1024) ----------------
    const size_t t = (size_t)(bid - 1028)*1024 + tid;   // 1572864 chunks
    const size_t i = t*8;
    const float* src;
    if (i < 3145728)       src = inw  + i;
    else if (i < 4194304)  src = outw + (i-3145728);
    else if (i < 8388608)  src = w1   + (i-4194304);
    else                   src = w2   + (i-8388608);
    float4 a = *(const float4*)src, bq = *(const float4*)(src+4);
    *(bf16x8_t*)(wbf + i) = pack8(a, bq);
  }
}

// ------------------------------------------------- mean over S (2-stage)
__global__ __launch_bounds__(256) void partial_kernel(const float* __restrict__ lh,
                                                      float* __restrict__ part){
  const int ph = blockIdx.x*256 + threadIdx.x;
  const int sc = blockIdx.y, b = blockIdx.z;
  const float* p = lh + ((size_t)b*512 + sc*64)*4096 + ph;
  float s0=0,s1=0,s2=0,s3=0;
  for (int j = 0; j < 64; j += 4){
    s0 += p[(size_t)(j+0)*4096];
    s1 += p[(size_t)(j+1)*4096];
    s2 += p[(size_t)(j+2)*4096];
    s3 += p[(size_t)(j+3)*4096];
  }
  part[(size_t)(b*8+sc)*4096 + ph] = (s0+s1)+(s2+s3);
}

__global__ __launch_bounds__(256) void combine_kernel(const float* __restrict__ part,
                                                      float* __restrict__ mlh){
  const int i = blockIdx.x*256 + threadIdx.x;
  const int b = i >> 12, ph = i & 4095;
  float s = 0;
#pragma unroll
  for (int sc = 0; sc < 8; ++sc) s += part[(size_t)(b*8+sc)*4096 + ph];
  mlh[i] = s * (1.0f/512.0f);
}

// ------------------------------------------------- agg = mean_lh @ fp_w.T + fp_b
__global__ __launch_bounds__(256) void agg_kernel(const float* __restrict__ mlh,
                                                  const float* __restrict__ fpw,
                                                  const float* __restrict__ fpb,
                                                  float* __restrict__ agg){
  const int o = blockIdx.x*4 + (threadIdx.x>>6);
  const int lane = threadIdx.x & 63;
  const int b = o >> 10, d = o & 1023;
  const float* mp = mlh + b*4096;
  const float* wp = fpw + (size_t)d*4096;
  float s = 0;
#pragma unroll 4
  for (int j = 0; j < 64; ++j){
    int ph = lane + j*64;
    s += mp[ph] * wp[ph];
  }
  s = wredsum(s);
  if (lane == 0) agg[o] = s + fpb[d];
}

// ------------------------------------------------- LayerNorm (optional +pos), bf16 out
__global__ __launch_bounds__(256) void ln_kernel(const float* __restrict__ x,
                                                 const float* __restrict__ pos,
                                                 const float* __restrict__ w,
                                                 const float* __restrict__ bb,
                                                 __bf16* __restrict__ out){
  const int tok = blockIdx.x, g = tok & 127, t = threadIdx.x;
  const int lane = t & 63, wv = t >> 6;
  const float* xr = x + (size_t)tok*1024;
  float v[4];
#pragma unroll
  for (int j = 0; j < 4; ++j){
    int d = t + j*256;
    float val = xr[d];
    if (pos) val += pos[g*1024 + d];
    v[j] = val;
  }
  __shared__ float r1[4], r2[4];
  float s = wredsum(v[0]+v[1]+v[2]+v[3]);
  if (lane == 0) r1[wv] = s;
  __syncthreads();
  const float mean = (r1[0]+r1[1]+r1[2]+r1[3]) * (1.0f/1024.0f);
  float sq = 0;
#pragma unroll
  for (int j = 0; j < 4; ++j){ float d0 = v[j]-mean; sq += d0*d0; }
  sq = wredsum(sq);
  if (lane == 0) r2[wv] = sq;
  __syncthreads();
  const float var = (r2[0]+r2[1]+r2[2]+r2[3]) * (1.0f/1024.0f);
  const float rs = rsqrtf(var + 1e-5f);
#pragma unroll
  for (int j = 0; j < 4; ++j){
    int d = t + j*256;
    out[(size_t)tok*1024 + d] = (__bf16)((v[j]-mean)*rs*w[d] + bb[d]);
  }
}

// ------------------------------------------------- bf16 MFMA split-K GEMM, 128x128 tile, BK=64
// (validated R10: single-buffer 2-barrier, XOR quarter-swizzle w/ pre-swizzled global source)
__global__ __launch_bounds__(256) void gemm_sk(
  const __bf16* __restrict__ A, const __bf16* __restrict__ W,
  float* __restrict__ parts, int M, int N, int K, int kc)
{
  __shared__ __bf16 As[128*64];
  __shared__ __bf16 Ws[128*64];
  const int n0 = blockIdx.x*128, m0 = blockIdx.y*128, z = blockIdx.z;
  const int tid = threadIdx.x;
  const int lane = tid & 63, w = tid >> 6;
  const int wm = w >> 1, wn = w & 1;
  const int lr = lane & 15, g = lane >> 4;
  const int kbeg = z*kc;
  const int c0 = tid, c1 = tid+256, c2 = tid+512, c3 = tid+768;
  const int r0 = c0>>3, r1 = c1>>3, r2 = c2>>3, r3 = c3>>3;
  const int s0 = ((c0&7) ^ (r0&7))*8, s1 = ((c1&7) ^ (r1&7))*8;
  const int s2 = ((c2&7) ^ (r2&7))*8, s3 = ((c3&7) ^ (r3&7))*8;
  const __bf16* pa0 = A + (size_t)(m0+r0)*K + kbeg + s0;
  const __bf16* pa1 = A + (size_t)(m0+r1)*K + kbeg + s1;
  const __bf16* pa2 = A + (size_t)(m0+r2)*K + kbeg + s2;
  const __bf16* pa3 = A + (size_t)(m0+r3)*K + kbeg + s3;
  const __bf16* pw0 = W + (size_t)(n0+r0)*K + kbeg + s0;
  const __bf16* pw1 = W + (size_t)(n0+r1)*K + kbeg + s1;
  const __bf16* pw2 = W + (size_t)(n0+r2)*K + kbeg + s2;
  const __bf16* pw3 = W + (size_t)(n0+r3)*K + kbeg + s3;
  f32x4_t acc[4][4] = {};
  for (int k0 = 0; k0 < kc; k0 += 64){
    __syncthreads();
    gload16(pa0 + k0, &As[c0*8]);
    gload16(pa1 + k0, &As[c1*8]);
    gload16(pa2 + k0, &As[c2*8]);
    gload16(pa3 + k0, &As[c3*8]);
    gload16(pw0 + k0, &Ws[c0*8]);
    gload16(pw1 + k0, &Ws[c1*8]);
    gload16(pw2 + k0, &Ws[c2*8]);
    gload16(pw3 + k0, &Ws[c3*8]);
    __syncthreads();
#pragma unroll
    for (int ks2 = 0; ks2 < 2; ++ks2){
      bf16x8_t af[4], bf[4];
#pragma unroll
      for (int f = 0; f < 4; ++f){
        const int ra = wm*64 + f*16 + lr;
        const int rb = wn*64 + f*16 + lr;
        const int lq = ks2*4 + g;
        af[f] = *(bf16x8_t*)&As[ra*64 + (lq ^ (ra&7))*8];
        bf[f] = *(bf16x8_t*)&Ws[rb*64 + (lq ^ (rb&7))*8];
      }
#pragma unroll
      for (int i = 0; i < 4; ++i)
#pragma unroll
        for (int j = 0; j < 4; ++j)
          acc[i][j] = __builtin_amdgcn_mfma_f32_16x16x32_bf16(af[i], bf[j], acc[i][j], 0, 0, 0);
    }
  }
  float* C = parts + (size_t)z*M*N;
#pragma unroll
  for (int i = 0; i < 4; ++i)
#pragma unroll
    for (int j = 0; j < 4; ++j)
#pragma unroll
      for (int r = 0; r < 4; ++r){
        const int row = m0 + wm*64 + i*16 + g*4 + r;
        const int col = n0 + wn*64 + j*16 + lr;
        C[(size_t)row*N + col] = acc[i][j][r];
      }
}

// ------------------------------------------------- combines (validated)
__global__ __launch_bounds__(256) void comb_qkv(const float* __restrict__ parts,
                                                const float* __restrict__ bias,
                                                __bf16* __restrict__ out){
  const int i = blockIdx.x*256 + threadIdx.x;   // < 1572864
  const int col = i % 3072;
  out[i] = (__bf16)(parts[i] + parts[1572864 + i] + bias[col]);
}

__global__ __launch_bounds__(256) void comb_gelu(const float* __restrict__ parts,
                                                 const float* __restrict__ bias,
                                                 __bf16* __restrict__ out){
  const int i = blockIdx.x*256 + threadIdx.x;   // < 2097152
  const int col = i & 4095;
  float v = parts[i] + parts[2097152 + i] + bias[col];
  v = v * 0.5f * (1.0f + erff(v * 0.70710678118654752440f));
  out[i] = (__bf16)v;
}

// residual add (+bias, nsplit fp32 partials) into x, then optional LayerNorm -> bf16 xn.
// MODE 0: LN; MODE 1: LN with pos added to LN input; MODE 2: no LN, emit bf16 copy of x.
template<int MODE>
__global__ __launch_bounds__(256) void comb_res_ln(const float* __restrict__ parts, int nsplit,
                                                   const float* __restrict__ bias,
                                                   const float* __restrict__ pos,
                                                   const float* __restrict__ lw,
                                                   const float* __restrict__ lb,
                                                   float* __restrict__ x,
                                                   __bf16* __restrict__ xn){
  const int tok = blockIdx.x, gi = tok & 127, t = threadIdx.x;
  const int lane = t & 63, wv = t >> 6;
  float v[4];
#pragma unroll
  for (int j = 0; j < 4; ++j){
    const int d = t + j*256;
    const size_t idx = (size_t)tok*1024 + d;
    float s = 0;
    for (int z = 0; z < nsplit; ++z) s += parts[(size_t)z*524288 + idx];
    float val = x[idx] + s + bias[d];
    x[idx] = val;
    v[j] = val;
  }
  if (MODE == 2){
#pragma unroll
    for (int j = 0; j < 4; ++j){
      const int d = t + j*256;
      xn[(size_t)tok*1024 + d] = (__bf16)v[j];
    }
    return;
  }
  float u[4];
#pragma unroll
  for (int j = 0; j < 4; ++j){
    const int d = t + j*256;
    u[j] = v[j] + (MODE == 1 ? pos[gi*1024 + d] : 0.0f);
  }
  __shared__ float r1[4], r2[4];
  float s1 = wredsum(u[0]+u[1]+u[2]+u[3]);
  if (lane == 0) r1[wv] = s1;
  __syncthreads();
  const float mean = (r1[0]+r1[1]+r1[2]+r1[3]) * (1.0f/1024.0f);
  float sq = 0;
#pragma unroll
  for (int j = 0; j < 4; ++j){ float d0 = u[j]-mean; sq += d0*d0; }
  sq = wredsum(sq);
  if (lane == 0) r2[wv] = sq;
  __syncthreads();
  const float var = (r2[0]+r2[1]+r2[2]+r2[3]) * (1.0f/1024.0f);
  const float rs = rsqrtf(var + 1e-5f);
#pragma unroll
  for (int j = 0; j < 4; ++j){
    const int d = t + j*256;
    xn[(size_t)tok*1024 + d] = (__bf16)((u[j]-mean)*rs*lw[d] + lb[d]);
  }
}

// ------------------------------------------------- fused attention v2 + piggybacked weight conv
// blocks 0..63: attention per (b,h,half) (validated R6).
// blocks >=64: fp32->bf16 conversion of the NEXT layer's weights (hides on idle CUs).
// cs1==nullptr -> single flat array at cs0 (used for c1 at layer 3).
__global__ __launch_bounds__(256) void attn_fused(const __bf16* __restrict__ qkv,
                                                  __bf16* __restrict__ O,
                                                  const float* __restrict__ cs0,
                                                  const float* __restrict__ cs1,
                                                  const float* __restrict__ cs2,
                                                  const float* __restrict__ cs3,
                                                  __bf16* __restrict__ cdst,
                                                  int nch){
  if (blockIdx.x >= 64){
    const int t = (blockIdx.x - 64)*256 + threadIdx.x;
    if (t < nch){
      const size_t i = (size_t)t*8;
      const float* src;
      if (cs1 == nullptr){
        src = cs0 + i;
      } else {
        if (i < 3145728)       src = cs0 + i;
        else if (i < 4194304)  src = cs1 + (i-3145728);
        else if (i < 8388608)  src = cs2 + (i-4194304);
        else                   src = cs3 + (i-8388608);
      }
      float4 a = *(const float4*)src, bq = *(const float4*)(src+4);
      *(bf16x8_t*)(cdst + i) = pack8(a, bq);
    }
    return;
  }
  const int bh = blockIdx.x >> 1, half = blockIdx.x & 1;
  const int b = bh>>3, h = bh&7;
  const int tid = threadIdx.x, w = tid>>6, lane = tid&63;
  const int lr = lane&15, g = lane>>4;
  __shared__ __bf16 vt[128*128];    // V^T swizzled
  __shared__ __bf16 pl[4*2048];     // per-wave P (16x128), swizzled
  {
    const int n = tid >> 1, kh = tid & 1;
    const __bf16* vbase = qkv + (size_t)(b*128)*3072 + 2048 + h*128 + n;
#pragma unroll
    for (int jb = 0; jb < 8; ++jb){
      bf16x8_t pk;
#pragma unroll
      for (int e = 0; e < 8; ++e) pk[e] = vbase[(size_t)(kh*64 + jb*8 + e)*3072];
      const int cb = kh*8 + jb;
      *(bf16x8_t*)&vt[n*128 + ((cb ^ (n&7)) * 8)] = pk;
    }
  }
  const __bf16* qbase = qkv + (size_t)(b*128)*3072 + h*128;
  const __bf16* kbase = qbase + 1024;
  const int qrow0 = half*64 + w*16;
  f32x4_t acc[8] = {};
#pragma unroll
  for (int ks = 0; ks < 4; ++ks){
    bf16x8_t aq, bk[8];
    aq = *(const bf16x8_t*)(qbase + (size_t)(qrow0 + lr)*3072 + ks*32 + g*8);
#pragma unroll
    for (int j = 0; j < 8; ++j)
      bk[j] = *(const bf16x8_t*)(kbase + (size_t)(j*16 + lr)*3072 + ks*32 + g*8);
#pragma unroll
    for (int j = 0; j < 8; ++j)
      acc[j] = __builtin_amdgcn_mfma_f32_16x16x32_bf16(aq, bk[j], acc[j], 0, 0, 0);
  }
  __syncthreads();
  const float scale = 0.088388347648318447f;  // 1/sqrt(128)
#pragma unroll
  for (int r = 0; r < 4; ++r){
    const int row = g*4 + r;
    float sv[8];
    float mx = -1e30f;
#pragma unroll
    for (int j = 0; j < 8; ++j){ sv[j] = acc[j][r]*scale; mx = fmaxf(mx, sv[j]); }
#pragma unroll
    for (int o = 1; o < 16; o <<= 1) mx = fmaxf(mx, __shfl_xor(mx, o, 64));
    float s = 0;
#pragma unroll
    for (int j = 0; j < 8; ++j){ sv[j] = expf(sv[j]-mx); s += sv[j]; }
#pragma unroll
    for (int o = 1; o < 16; o <<= 1) s += __shfl_xor(s, o, 64);
    const float inv = 1.0f/s;
#pragma unroll
    for (int j = 0; j < 8; ++j){
      const int col = j*16 + lr;
      const int slot = (col>>3) ^ (row&7);
      pl[w*2048 + row*128 + slot*8 + (lr&7)] = (__bf16)(sv[j]*inv);
    }
  }
  __syncthreads();
  f32x4_t acc2[8] = {};
#pragma unroll
  for (int ks = 0; ks < 4; ++ks){
    bf16x8_t ap, bv[8];
    {
      const int row = lr;
      const int slot = (ks*4 + g) ^ (row&7);
      ap = *(bf16x8_t*)&pl[w*2048 + row*128 + slot*8];
    }
#pragma unroll
    for (int j = 0; j < 8; ++j){
      const int rowv = j*16 + lr;
      const int cb = ks*4 + g;
      bv[j] = *(bf16x8_t*)&vt[rowv*128 + ((cb ^ (rowv&7))*8)];
    }
#pragma unroll
    for (int j = 0; j < 8; ++j)
      acc2[j] = __builtin_amdgcn_mfma_f32_16x16x32_bf16(ap, bv[j], acc2[j], 0, 0, 0);
  }
#pragma unroll
  for (int j = 0; j < 8; ++j)
#pragma unroll
    for (int r = 0; r < 4; ++r){
      const int row = qrow0 + g*4 + r;
      const int col = j*16 + lr;
      O[(size_t)(b*128+row)*1024 + h*128 + col] = (__bf16)acc2[j][r];
    }
}

// ------------------------------------------------- head: c1 combine + BN + ReLU + c2 GEMV + centers
__global__ __launch_bounds__(256) void head_kernel(const float* __restrict__ parts,
                                                   const float* __restrict__ c1b,
                                                   const float* __restrict__ bnm,
                                                   const float* __restrict__ bnv,
                                                   const float* __restrict__ bng,
                                                   const float* __restrict__ bnb,
                                                   const float* __restrict__ c2w,
                                                   const float* __restrict__ c2b,
                                                   const float* __restrict__ centers,
                                                   float* __restrict__ out){
  const int tok = blockIdx.x, t = threadIdx.x;
  const int wv = t >> 6, lane = t & 63;
  __shared__ float hrow[1024];
#pragma unroll
  for (int j = 0; j < 4; ++j){
    const int d = t + j*256;
    const size_t idx = (size_t)tok*1024 + d;
    float s = 0;
#pragma unroll
    for (int z = 0; z < 8; ++z) s += parts[(size_t)z*524288 + idx];
    float v = s + c1b[d];
    v = (v - bnm[d]) * rsqrtf(bnv[d] + 1e-5f) * bng[d] + bnb[d];
    hrow[d] = fmaxf(v, 0.0f);
  }
  __syncthreads();
  for (int i = 0; i < 24; ++i){
    const int n = wv*24 + i;
    const float* wp = c2w + (size_t)n*1024;
    float s = 0;
#pragma unroll 4
    for (int j = 0; j < 16; ++j){
      const int k = lane + j*64;
      s += hrow[k] * wp[k];
    }
    s = wredsum(s);
    if (lane == 0) out[(size_t)tok*96 + n] = s + c2b[n] + centers[tok*3 + (n % 3)];
  }
}

// =================================================================
extern "C" void kernel_launch(void* const* d_in, const int* in_sizes, int n_in,
                              void* d_out, int out_size, void* d_ws, size_t ws_size,
                              hipStream_t stream){
  const float* lh   = (const float*)d_in[0];
  const float* pc   = (const float*)d_in[1];
  const float* fpw  = (const float*)d_in[2];
  const float* fpb  = (const float*)d_in[3];
  const float* spw  = (const float*)d_in[4];
  const float* spb  = (const float*)d_in[5];
  const float* pos  = (const float*)d_in[6];
  const float* ln1w = (const float*)d_in[7];
  const float* ln1b = (const float*)d_in[8];
  const float* inw  = (const float*)d_in[9];
  const float* inb  = (const float*)d_in[10];
  const float* outw = (const float*)d_in[11];
  const float* outb = (const float*)d_in[12];
  const float* ln2w = (const float*)d_in[13];
  const float* ln2b = (const float*)d_in[14];
  const float* w1   = (const float*)d_in[15];
  const float* b1   = (const float*)d_in[16];
  const float* w2   = (const float*)d_in[17];
  const float* b2   = (const float*)d_in[18];
  const float* c1w  = (const float*)d_in[19];
  const float* c1b  = (const float*)d_in[20];
  const float* bng  = (const float*)d_in[21];
  const float* bnbt = (const float*)d_in[22];
  const float* bnm  = (const float*)d_in[23];
  const float* bnv  = (const float*)d_in[24];
  const float* c2w  = (const float*)d_in[25];
  const float* c2b  = (const float*)d_in[26];
  float* out = (float*)d_out;

  // ---- workspace layout ----
  float* f = (float*)d_ws;
  float* parts = f;              f += 16*524288;  // split-K fp32 partials (32 MB)
  float* part  = f;              f += 131072;
  float* mlh   = f;              f += 16384;
  float* agg   = f;              f += 4096;
  float* x     = f;              f += 524288;     // residual stream fp32
  float* cent  = f;              f += 2048;       // centers (+pad)
  __bf16* bfp = (__bf16*)f;
  __bf16* xn   = bfp;            bfp += 524288;   // LN out bf16
  __bf16* qkv  = bfp;            bfp += 1572864;
  __bf16* obuf = bfp;            bfp += 524288;
  __bf16* hbf  = bfp;            bfp += 2097152;  // MLP hidden bf16
  __bf16* xbf  = bfp;            bfp += 524288;   // bf16 copy of final x
  __bf16* wbf  = bfp;            bfp += 51380224; // all weights bf16 (4 layers + c1 at +50331648)

  partial_kernel<<<dim3(16,8,4), 256, 0, stream>>>(lh, part);
  combine_kernel<<<64, 256, 0, stream>>>(part, mlh);
  agg_kernel<<<1024, 256, 0, stream>>>(mlh, fpw, fpb, agg);
  fused_front<<<2564, 1024, 0, stream>>>(pc, cent, agg, spw, spb, x,
                                         inw, outw, w1, w2, wbf);
  ln_kernel<<<512, 256, 0, stream>>>(x, pos, ln1w, ln1b, xn);

  for (int l = 0; l < 4; ++l){
    const __bf16* wl = wbf + (size_t)l*12582912;
    // qkv: 512x3072x1024, split-2 (192 blocks, 8 BK64-steps)
    gemm_sk<<<dim3(24,4,2), 256, 0, stream>>>(xn, wl, parts, 512, 3072, 1024, 512);
    comb_qkv<<<6144, 256, 0, stream>>>(parts, inb + l*3072, qkv);
    // attn (64 blocks) + piggybacked conversion of next layer's weights (or c1 at l=3)
    if (l < 3)
      attn_fused<<<64 + 6144, 256, 0, stream>>>(qkv, obuf,
          inw + (size_t)(l+1)*3145728, outw + (size_t)(l+1)*1048576,
          w1 + (size_t)(l+1)*4194304, w2 + (size_t)(l+1)*4194304,
          wbf + (size_t)(l+1)*12582912, 1572864);
    else
      attn_fused<<<64 + 512, 256, 0, stream>>>(qkv, obuf,
          c1w, nullptr, nullptr, nullptr, wbf + 50331648, 131072);
    // attn-out: 512x1024x1024, split-8 (256 blocks, 2 steps)
    gemm_sk<<<dim3(8,4,8), 256, 0, stream>>>(obuf, wl + 3145728, parts, 512, 1024, 1024, 128);
    comb_res_ln<0><<<512, 256, 0, stream>>>(parts, 8, outb + l*1024, nullptr,
                                            ln2w + l*1024, ln2b + l*1024, x, xn);
    // mlp1: 512x4096x1024, split-2 (256 blocks, 8 steps)
    gemm_sk<<<dim3(32,4,2), 256, 0, stream>>>(xn, wl + 4194304, parts, 512, 4096, 1024, 512);
    comb_gelu<<<8192, 256, 0, stream>>>(parts, b1 + l*4096, hbf);
    // mlp2: 512x1024x4096, split-8 (256 blocks, 8 steps)
    gemm_sk<<<dim3(8,4,8), 256, 0, stream>>>(hbf, wl + 8388608, parts, 512, 1024, 4096, 512);
    if (l < 3)
      comb_res_ln<1><<<512, 256, 0, stream>>>(parts, 8, b2 + l*1024, pos,
                                              ln1w + (l+1)*1024, ln1b + (l+1)*1024, x, xn);
    else
      comb_res_ln<2><<<512, 256, 0, stream>>>(parts, 8, b2 + l*1024, nullptr,
                                              nullptr, nullptr, x, xbf);
  }

  // c1: 512x1024x1024, split-8 (256 blocks, 2 steps); head fuses combine+BN+ReLU+c2+centers
  gemm_sk<<<dim3(8,4,8), 256, 0, stream>>>(xbf, wbf + 50331648, parts, 512, 1024, 1024, 128);
  head_kernel<<<512, 256, 0, stream>>>(parts, c1b, bnm, bnv, bng, bnbt, c2w, c2b, cent, out);
}